// Round 11
// baseline (945.094 us; speedup 1.0000x reference)
//
#include <hip/hip_runtime.h>
#include <math.h>

#define BB 8
#define NN 2048
#define DD 256
#define KNN 8
#define NPTS (BB*NN)        // 16384
#define NEDGE (NPTS*KNN)    // 131072
#define BN_EPS 1e-5f
#define NSH 64              // shadow copies for BN stats accumulation
#define PSH 32              // shadow copies for pooled max/min

// ---- workspace layout (float offsets) ----
// stats+pmaxs+sq contiguous -> single zero memset; pmins separate 0x7f memset.
#define OFF_X      0
#define OFF_FEAT   (OFF_X + NPTS*DD)
#define OFF_STATS  (OFF_FEAT + NPTS*3*DD)     // NSH x 1024
#define OFF_PMAXS  (OFF_STATS + NSH*1024)     // PSH x BB x 256
#define OFF_SQ     (OFF_PMAXS + PSH*BB*DD)    // NPTS
#define OFF_PMINS  (OFF_SQ + NPTS)            // PSH x BB x 256
#define OFF_IDX    (OFF_PMINS + PSH*BB*DD)
#define OFF_U      (OFF_IDX + NEDGE)
#define OFF_V      (OFF_U + NPTS*DD)
#define OFF_WU     (OFF_V + NPTS*DD)
#define OFF_W2P    (OFF_WU + DD*DD)
#define OFF_BIASP  (OFF_W2P + DD*DD)

// async global->LDS, 16B per lane; lbase must be wave-uniform, dest = lbase + lane*16B
__device__ __forceinline__ void gload_lds16(const float* g, float* lbase) {
#if defined(__has_builtin) && __has_builtin(__builtin_amdgcn_global_load_lds)
  __builtin_amdgcn_global_load_lds(
      (const __attribute__((address_space(1))) void*)(g),
      (__attribute__((address_space(3))) void*)(lbase),
      16, 0, 0);
#else
  int lane = threadIdx.x & 63;
  *(float4*)(lbase + lane*4) = *(const float4*)g;
#endif
}

// ---------------- per-point features: wave-per-point, 4 points/block
__global__ __launch_bounds__(256) void featurize(
    const int* __restrict__ cls, const float* __restrict__ colors, const float* __restrict__ positions,
    const float* __restrict__ ctab,
    const float* __restrict__ pW1, const float* __restrict__ pb1, const float* __restrict__ pW2, const float* __restrict__ pb2,
    const float* __restrict__ cW1, const float* __restrict__ cb1, const float* __restrict__ cW2, const float* __restrict__ cb2,
    float* __restrict__ feat)
{
  __shared__ float wbuf[4][64];   // per-wave: [0:32) colh, [32:64) posh
  int tid = threadIdx.x;
  int wv = tid >> 6, lane = tid & 63;
  int p = blockIdx.x*4 + wv;
  if (lane < 32) {
    float c0 = colors[p*3+0], c1 = colors[p*3+1], c2 = colors[p*3+2];
    wbuf[wv][lane] = fmaxf(c0*cW1[lane] + c1*cW1[32+lane] + c2*cW1[64+lane] + cb1[lane], 0.f);
  } else {
    int l = lane - 32;
    float q0 = positions[p*3+0], q1 = positions[p*3+1], q2 = positions[p*3+2];
    wbuf[wv][32+l] = fmaxf(q0*pW1[l] + q1*pW1[32+l] + q2*pW1[64+l] + pb1[l], 0.f);
  }
  __syncthreads();
  int c = lane*4;
  float4 ce4 = *(const float4*)&ctab[(size_t)cls[p]*DD + c];
  float4 col4 = *(const float4*)&cb2[c];
  float4 pos4 = *(const float4*)&pb2[c];
  #pragma unroll
  for (int k = 0; k < 32; k++) {
    float ch = wbuf[wv][k], ph = wbuf[wv][32+k];
    float4 cw = *(const float4*)&cW2[k*DD + c];
    float4 pw = *(const float4*)&pW2[k*DD + c];
    col4.x += ch*cw.x; col4.y += ch*cw.y; col4.z += ch*cw.z; col4.w += ch*cw.w;
    pos4.x += ph*pw.x; pos4.y += ph*pw.y; pos4.z += ph*pw.z; pos4.w += ph*pw.w;
  }
  col4.x = fmaxf(col4.x, 0.f); col4.y = fmaxf(col4.y, 0.f);
  col4.z = fmaxf(col4.z, 0.f); col4.w = fmaxf(col4.w, 0.f);
  pos4.x = fmaxf(pos4.x, 0.f); pos4.y = fmaxf(pos4.y, 0.f);
  pos4.z = fmaxf(pos4.z, 0.f); pos4.w = fmaxf(pos4.w, 0.f);
  float sce  = ce4.x*ce4.x + ce4.y*ce4.y + ce4.z*ce4.z + ce4.w*ce4.w;
  float scol = col4.x*col4.x + col4.y*col4.y + col4.z*col4.z + col4.w*col4.w;
  float spos = pos4.x*pos4.x + pos4.y*pos4.y + pos4.z*pos4.z + pos4.w*pos4.w;
  #pragma unroll
  for (int m = 1; m <= 32; m <<= 1) {
    sce  += __shfl_xor(sce,  m, 64);
    scol += __shfl_xor(scol, m, 64);
    spos += __shfl_xor(spos, m, 64);
  }
  float ice = 1.f / fmaxf(sqrtf(sce),  1e-12f);
  float icl = 1.f / fmaxf(sqrtf(scol), 1e-12f);
  float ips = 1.f / fmaxf(sqrtf(spos), 1e-12f);
  float* fp = feat + (size_t)p*768;
  *(float4*)&fp[c]       = make_float4(ce4.x*ice,  ce4.y*ice,  ce4.z*ice,  ce4.w*ice);
  *(float4*)&fp[256 + c] = make_float4(col4.x*icl, col4.y*icl, col4.z*icl, col4.w*icl);
  *(float4*)&fp[512 + c] = make_float4(pos4.x*ips, pos4.y*ips, pos4.z*ips, pos4.w*ips);
}

// ---------------- generic 64x64-tile GEMM: C[M,256] = act(A[M,KD] @ W[KD,256] (+bias))
// Optional fused row sum-of-squares (atomicAdd into sq, 4 contenders/row).
template<int KD, bool RELU, bool HASBIAS, bool SQOUT>
__global__ __launch_bounds__(256) void gemm64(
    const float* __restrict__ A, const float* __restrict__ W, const float* __restrict__ bias,
    float* __restrict__ C, float* __restrict__ sqo)
{
  __shared__ float aT[32][68];
  __shared__ float bS[32*64];
  int tid = threadIdx.x;
  int tx = tid & 15, ty = tid >> 4;
  int rowbase = blockIdx.x * 64;
  int colbase = blockIdx.y * 64;
  int sr = tid >> 2, sk = (tid & 3) * 8;
  int lane = tid & 63, wv = tid >> 6;
  float acc[4][4] = {};
  for (int kc = 0; kc < KD; kc += 32) {
    const float* ap = A + (size_t)(rowbase + sr)*KD + kc + sk;
    float4 a0 = *(const float4*)ap;
    float4 a1 = *(const float4*)(ap + 4);
    __syncthreads();
    #pragma unroll
    for (int r = 0; r < 2; r++) {
      int R0 = r*16 + wv*4;
      gload_lds16(W + (size_t)(kc + R0 + (lane >> 4))*DD + colbase + (lane & 15)*4,
                  &bS[R0*64]);
    }
    aT[sk+0][sr]=a0.x; aT[sk+1][sr]=a0.y; aT[sk+2][sr]=a0.z; aT[sk+3][sr]=a0.w;
    aT[sk+4][sr]=a1.x; aT[sk+5][sr]=a1.y; aT[sk+6][sr]=a1.z; aT[sk+7][sr]=a1.w;
    __syncthreads();
    #pragma unroll
    for (int k = 0; k < 32; k++) {
      float4 av = *(const float4*)&aT[k][ty*4];
      float4 bv = *(const float4*)&bS[k*64 + tx*4];
      float a_[4] = {av.x, av.y, av.z, av.w};
      float b_[4] = {bv.x, bv.y, bv.z, bv.w};
      #pragma unroll
      for (int rr = 0; rr < 4; rr++)
        #pragma unroll
        for (int cc = 0; cc < 4; cc++)
          acc[rr][cc] += a_[rr]*b_[cc];
    }
  }
  float sqp[4];
  #pragma unroll
  for (int rr = 0; rr < 4; rr++) {
    int row = rowbase + ty*4 + rr;
    float o[4];
    #pragma unroll
    for (int cc = 0; cc < 4; cc++) {
      float v = acc[rr][cc];
      if (HASBIAS) v += bias[colbase + tx*4 + cc];
      if (RELU) v = fmaxf(v, 0.f);
      o[cc] = v;
    }
    if (SQOUT) sqp[rr] = o[0]*o[0] + o[1]*o[1] + o[2]*o[2] + o[3]*o[3];
    *(float4*)&C[(size_t)row*DD + colbase + tx*4] = make_float4(o[0],o[1],o[2],o[3]);
  }
  if (SQOUT) {
    #pragma unroll
    for (int rr = 0; rr < 4; rr++) {
      #pragma unroll
      for (int m = 1; m <= 8; m <<= 1) sqp[rr] += __shfl_xor(sqp[rr], m, 64);
    }
    if (tx == 0) {
      #pragma unroll
      for (int rr = 0; rr < 4; rr++)
        atomicAdd(&sqo[rowbase + ty*4 + rr], sqp[rr]);
    }
  }
}

// ---------------- Wu = W1_top - W1_bot
__global__ __launch_bounds__(256) void prep_wu(const float* __restrict__ gW1, float* __restrict__ Wu) {
  int i = blockIdx.x*256 + threadIdx.x;
  Wu[i] = gW1[i] - gW1[i + DD*DD];
}

// ---------------- fused u/v GEMM: u = x@Wu, v = x@W1bot (stage x once, weights via DMA)
__global__ __launch_bounds__(256) void gemmuv(
    const float* __restrict__ A, const float* __restrict__ Wu, const float* __restrict__ Wb,
    float* __restrict__ U, float* __restrict__ V)
{
  __shared__ float aT[32][68];
  __shared__ float bU[32*64];
  __shared__ float bV[32*64];
  int tid = threadIdx.x;
  int tx = tid & 15, ty = tid >> 4;
  int rowbase = blockIdx.x * 64;
  int colbase = blockIdx.y * 64;
  int sr = tid >> 2, sk = (tid & 3) * 8;
  int lane = tid & 63, wv = tid >> 6;
  float accU[4][4] = {}, accV[4][4] = {};
  for (int kc = 0; kc < DD; kc += 32) {
    const float* ap = A + (size_t)(rowbase + sr)*DD + kc + sk;
    float4 a0 = *(const float4*)ap;
    float4 a1 = *(const float4*)(ap + 4);
    __syncthreads();
    #pragma unroll
    for (int r = 0; r < 2; r++) {
      int R0 = r*16 + wv*4;
      size_t goff = (size_t)(kc + R0 + (lane >> 4))*DD + colbase + (lane & 15)*4;
      gload_lds16(Wu + goff, &bU[R0*64]);
      gload_lds16(Wb + goff, &bV[R0*64]);
    }
    aT[sk+0][sr]=a0.x; aT[sk+1][sr]=a0.y; aT[sk+2][sr]=a0.z; aT[sk+3][sr]=a0.w;
    aT[sk+4][sr]=a1.x; aT[sk+5][sr]=a1.y; aT[sk+6][sr]=a1.z; aT[sk+7][sr]=a1.w;
    __syncthreads();
    #pragma unroll
    for (int k = 0; k < 32; k++) {
      float4 av = *(const float4*)&aT[k][ty*4];
      float4 bu = *(const float4*)&bU[k*64 + tx*4];
      float4 bv = *(const float4*)&bV[k*64 + tx*4];
      float a_[4] = {av.x, av.y, av.z, av.w};
      float u_[4] = {bu.x, bu.y, bu.z, bu.w};
      float v_[4] = {bv.x, bv.y, bv.z, bv.w};
      #pragma unroll
      for (int rr = 0; rr < 4; rr++)
        #pragma unroll
        for (int cc = 0; cc < 4; cc++) {
          accU[rr][cc] += a_[rr]*u_[cc];
          accV[rr][cc] += a_[rr]*v_[cc];
        }
    }
  }
  #pragma unroll
  for (int rr = 0; rr < 4; rr++) {
    int row = rowbase + ty*4 + rr;
    *(float4*)&U[(size_t)row*DD + colbase + tx*4] =
        make_float4(accU[rr][0], accU[rr][1], accU[rr][2], accU[rr][3]);
    *(float4*)&V[(size_t)row*DD + colbase + tx*4] =
        make_float4(accV[rr][0], accV[rr][1], accV[rr][2], accV[rr][3]);
  }
}

// ---------------- kNN partial: per (batch, 64-row i-tile, j-quarter), keep 8 smallest d
// R10-proven body (dt aliased onto aT/bT, XOR-16 staging swizzle, LDS 17.9 KB).
__global__ __launch_bounds__(256) void knnk(const float* __restrict__ x, const float* __restrict__ sq,
                                            float* __restrict__ pdg, int* __restrict__ pjg)
{
  __shared__ float smem[4480];
  float (*aT)[68] = (float(*)[68])smem;
  float (*bT)[68] = (float(*)[68])(smem + 2176);
  float (*dt)[65] = (float(*)[65])smem;       // aliases aT/bT (dead when dt is live)
  float* sqI = smem + 4352;
  float* sqJ = smem + 4416;
  int tid = threadIdx.x;
  int q  = blockIdx.x & 3;
  int it = (blockIdx.x >> 2) & 31;
  int bb = blockIdx.x >> 7;
  int ibase = it * 64;
  const float* xb  = x  + (size_t)bb*NN*DD;
  const float* sqb = sq + (size_t)bb*NN;
  int tx = tid & 15, ty = tid >> 4;
  int sr = tid >> 2, sk = (tid & 3) * 8;
  int srw = sr ^ ((tid & 1) << 4);   // staging-write swizzle (breaks 4-way bank conflict)
  int selrow = tid & 63, selseg = tid >> 6;
  float bd[8]; int bj[8];
  #pragma unroll
  for (int s = 0; s < 8; s++) { bd[s] = 3.4e38f; bj[s] = 0; }
  if (tid < 64) sqI[tid] = sqb[ibase + tid];
  for (int jt = 0; jt < 8; jt++) {
    int jbase = q*512 + jt*64;
    float acc[4][4] = {};
    for (int kc = 0; kc < DD; kc += 32) {
      const float* ap = xb + (size_t)(ibase + sr)*DD + kc + sk;
      float4 a0 = *(const float4*)ap;
      float4 a1 = *(const float4*)(ap + 4);
      const float* bp = xb + (size_t)(jbase + sr)*DD + kc + sk;
      float4 b0  = *(const float4*)bp;
      float4 b1v = *(const float4*)(bp + 4);
      float sjv = 0.f;
      if (kc == 0 && tid < 64) sjv = sqb[jbase + tid];
      __syncthreads();
      aT[sk+0][srw]=a0.x; aT[sk+1][srw]=a0.y; aT[sk+2][srw]=a0.z; aT[sk+3][srw]=a0.w;
      aT[sk+4][srw]=a1.x; aT[sk+5][srw]=a1.y; aT[sk+6][srw]=a1.z; aT[sk+7][srw]=a1.w;
      bT[sk+0][srw]=b0.x; bT[sk+1][srw]=b0.y; bT[sk+2][srw]=b0.z; bT[sk+3][srw]=b0.w;
      bT[sk+4][srw]=b1v.x; bT[sk+5][srw]=b1v.y; bT[sk+6][srw]=b1v.z; bT[sk+7][srw]=b1v.w;
      if (kc == 0 && tid < 64) sqJ[tid] = sjv;
      __syncthreads();
      #pragma unroll
      for (int k = 0; k < 32; k++) {
        int rsw = ((k >> 3) & 1) << 4;
        float4 av = *(const float4*)&aT[k][(ty*4) ^ rsw];
        float4 bv = *(const float4*)&bT[k][(tx*4) ^ rsw];
        float a_[4] = {av.x, av.y, av.z, av.w};
        float b_[4] = {bv.x, bv.y, bv.z, bv.w};
        #pragma unroll
        for (int rr = 0; rr < 4; rr++)
          #pragma unroll
          for (int cc = 0; cc < 4; cc++)
            acc[rr][cc] += a_[rr]*b_[cc];
      }
    }
    __syncthreads();   // aT/bT reads done before dt (aliased) writes
    #pragma unroll
    for (int rr = 0; rr < 4; rr++)
      #pragma unroll
      for (int cc = 0; cc < 4; cc++)
        dt[ty*4+rr][tx*4+cc] = sqI[ty*4+rr] + sqJ[tx*4+cc] - 2.f*acc[rr][cc];
    __syncthreads();
    int cb = selseg*16;
    #pragma unroll
    for (int s = 0; s < 16; s++) {
      float dv = dt[selrow][cb + s];
      if (dv < bd[7]) {
        bd[7] = dv; bj[7] = jbase + cb + s;
        #pragma unroll
        for (int t = 7; t >= 1; t--) {
          if (bd[t] < bd[t-1]) {
            float td = bd[t]; bd[t] = bd[t-1]; bd[t-1] = td;
            int   tj = bj[t]; bj[t] = bj[t-1]; bj[t-1] = tj;
          }
        }
      }
    }
    __syncthreads();   // dt reads done before next tile's staging (aliased) writes
  }
  // stage per-thread lists in LDS (overlay aT/bT)
  float* pdl = &smem[0];
  int*   pjl = (int*)&smem[2176];
  #pragma unroll
  for (int s = 0; s < 8; s++) {
    pdl[tid*8 + s] = bd[s];
    pjl[tid*8 + s] = bj[s];
  }
  __syncthreads();
  if (tid < 64) {
    float md[8]; int mj[8];
    #pragma unroll
    for (int s = 0; s < 8; s++) { md[s] = 3.4e38f; mj[s] = 0; }
    #pragma unroll 1
    for (int g = 0; g < 4; g++) {
      int base = (g*64 + tid)*8;
      #pragma unroll
      for (int s = 0; s < 8; s++) {
        float dv = pdl[base + s];
        if (dv < md[7]) {
          md[7] = dv; mj[7] = pjl[base + s];
          #pragma unroll
          for (int t = 7; t >= 1; t--) {
            if (md[t] < md[t-1]) {
              float td = md[t]; md[t] = md[t-1]; md[t-1] = td;
              int   tj = mj[t]; mj[t] = mj[t-1]; mj[t-1] = tj;
            }
          }
        }
      }
    }
    size_t gbase = ((size_t)(bb*NN + ibase + tid))*32 + (size_t)q*8;
    #pragma unroll
    for (int s = 0; s < 8; s++) {
      pdg[gbase + s] = md[s];
      pjg[gbase + s] = bb*NN + mj[s];
    }
  }
}

// ---------------- merge 4 quarter-lists per point -> final 8 neighbor indices
__global__ __launch_bounds__(256) void knnmerge(const float* __restrict__ pdg, const int* __restrict__ pjg,
                                                int* __restrict__ idxg)
{
  int p = blockIdx.x*256 + threadIdx.x;
  float md[8]; int mj[8];
  #pragma unroll
  for (int s = 0; s < 8; s++) { md[s] = 3.4e38f; mj[s] = 0; }
  size_t base = (size_t)p*32;
  #pragma unroll 1
  for (int s = 0; s < 32; s++) {
    float dv = pdg[base + s];
    if (dv < md[7]) {
      md[7] = dv; mj[7] = pjg[base + s];
      #pragma unroll
      for (int t = 7; t >= 1; t--) {
        if (md[t] < md[t-1]) {
          float td = md[t]; md[t] = md[t-1]; md[t-1] = td;
          int   tj = mj[t]; mj[t] = mj[t-1]; mj[t-1] = tj;
        }
      }
    }
  }
  #pragma unroll
  for (int s = 0; s < 8; s++) idxg[(size_t)p*8 + s] = mj[s];
}

// ---------------- BN1 stats: h1 = relu(u_i + v_j + b1), shadow-accumulator atomics
// 1024 blocks (16 nodes each) for gather-latency hiding.
__global__ __launch_bounds__(256) void bn1stats(const float* __restrict__ u, const float* __restrict__ v,
    const int* __restrict__ idxg, const float* __restrict__ b1, float* __restrict__ stats)
{
  __shared__ int jL[128];
  int c = threadIdx.x;
  int n0 = blockIdx.x * 16;
  if (c < 128) jL[c] = idxg[(size_t)n0*8 + c];
  __syncthreads();
  float b1c = b1[c];
  float s = 0.f, s2 = 0.f;
  #pragma unroll 1
  for (int n = 0; n < 16; n++) {
    float uc = u[(size_t)(n0 + n)*DD + c];
    #pragma unroll
    for (int e = 0; e < 8; e++) {
      int j = jL[n*8 + e];
      float h = fmaxf(uc + v[(size_t)j*DD + c] + b1c, 0.f);
      s += h; s2 += h*h;
    }
  }
  int row = blockIdx.x & (NSH - 1);
  atomicAdd(&stats[row*1024 + c], s);
  atomicAdd(&stats[row*1024 + 256 + c], s2);
}

// ---------------- fold BN1 into layer-2 weights: W2' = diag(s1) W2 ; bias' = b2 + t1.W2
__global__ __launch_bounds__(256) void prep2(const float* __restrict__ stats, const float* __restrict__ g1,
    const float* __restrict__ be1, const float* __restrict__ gW2, const float* __restrict__ gb2,
    float* __restrict__ W2p, float* __restrict__ biasp)
{
  __shared__ float s1L[256], t1L[256];
  int tid = threadIdx.x;
  const float inv = 1.f / (float)NEDGE;
  float sm = 0.f, sq2 = 0.f;
  #pragma unroll 1
  for (int r = 0; r < NSH; r++) {
    sm  += stats[r*1024 + tid];
    sq2 += stats[r*1024 + 256 + tid];
  }
  float m = sm * inv;
  float var = sq2*inv - m*m;
  float s1 = g1[tid] / sqrtf(var + BN_EPS);
  s1L[tid] = s1; t1L[tid] = be1[tid] - m*s1;
  __syncthreads();
  float bacc = gb2[tid];
  for (int k = 0; k < DD; k++) {
    float w = gW2[k*DD + tid];
    W2p[k*DD + tid] = s1L[k]*w;
    bacc += t1L[k]*w;
  }
  biasp[tid] = bacc;
}

// ---------------- edge GEMM: h2 = relu( relu(u_i+v_j+b1) @ W2' + bias' )
// BK=16 chunks + epilogue reduction arrays aliased onto dead bS:
// LDS ~21 KB -> ~5 blocks/CU (was 49 KB / 3 blocks).
__global__ __launch_bounds__(256) void edgek(
    const float* __restrict__ u, const float* __restrict__ v, const int* __restrict__ idxg,
    const float* __restrict__ b1, const float* __restrict__ W2p, const float* __restrict__ biasp,
    float* __restrict__ pmaxs, float* __restrict__ pmins, float* __restrict__ stats)
{
  __shared__ float aT[16][68];
  __shared__ float bS[16*256];    // 16 KB; epilogue redS/redQ alias here
  __shared__ int   jL[64];
  int tid = threadIdx.x;
  int tx = tid & 15, ty = tid >> 4;
  int rowbase = blockIdx.x * 64;
  if (tid < 64) jL[tid] = idxg[rowbase + tid];
  __syncthreads();
  int sr = tid >> 2, sk = (tid & 3) * 4;
  int iu = (rowbase + sr) >> 3;
  int lane = tid & 63, wv = tid >> 6;
  int jv = jL[sr];
  const float* urow = u + (size_t)iu*DD;
  const float* vrow = v + (size_t)jv*DD;
  float acc[4][16] = {};
  for (int kc = 0; kc < DD; kc += 16) {
    float4 u0 = *(const float4*)(urow + kc + sk);
    float4 v0 = *(const float4*)(vrow + kc + sk);
    float4 c0 = *(const float4*)&b1[kc + sk];
    __syncthreads();
    #pragma unroll
    for (int rI = 0; rI < 4; rI++) {
      int R = rI*4 + wv;
      gload_lds16(W2p + (size_t)(kc + R)*DD + lane*4, &bS[R*256]);
    }
    aT[sk+0][sr] = fmaxf(u0.x+v0.x+c0.x, 0.f);
    aT[sk+1][sr] = fmaxf(u0.y+v0.y+c0.y, 0.f);
    aT[sk+2][sr] = fmaxf(u0.z+v0.z+c0.z, 0.f);
    aT[sk+3][sr] = fmaxf(u0.w+v0.w+c0.w, 0.f);
    __syncthreads();
    #pragma unroll
    for (int k = 0; k < 16; k++) {
      float4 av = *(const float4*)&aT[k][ty*4];
      float a_[4] = {av.x, av.y, av.z, av.w};
      #pragma unroll
      for (int q = 0; q < 4; q++) {
        float4 bv = *(const float4*)&bS[k*256 + q*64 + tx*4];
        float b_[4] = {bv.x, bv.y, bv.z, bv.w};
        #pragma unroll
        for (int rr = 0; rr < 4; rr++)
          #pragma unroll
          for (int cc = 0; cc < 4; cc++)
            acc[rr][q*4+cc] += a_[rr]*b_[cc];
      }
    }
  }
  // epilogue
  float mx[16], mn[16], sS[16], sQ[16];
  #pragma unroll
  for (int q4 = 0; q4 < 4; q4++) {
    #pragma unroll
    for (int cc = 0; cc < 4; cc++) {
      int col = q4*64 + tx*4 + cc;
      float bp = biasp[col];
      int q = q4*4 + cc;
      float h0 = fmaxf(acc[0][q] + bp, 0.f);
      float h1 = fmaxf(acc[1][q] + bp, 0.f);
      float h2 = fmaxf(acc[2][q] + bp, 0.f);
      float h3 = fmaxf(acc[3][q] + bp, 0.f);
      mx[q] = fmaxf(fmaxf(h0,h1), fmaxf(h2,h3));
      mn[q] = fminf(fminf(h0,h1), fminf(h2,h3));
      sS[q] = h0+h1+h2+h3;
      sQ[q] = h0*h0+h1*h1+h2*h2+h3*h3;
    }
  }
  #pragma unroll
  for (int q = 0; q < 16; q++) {
    mx[q] = fmaxf(mx[q], __shfl_xor(mx[q], 16, 64));
    mx[q] = fmaxf(mx[q], __shfl_xor(mx[q], 32, 64));
    mn[q] = fminf(mn[q], __shfl_xor(mn[q], 16, 64));
    mn[q] = fminf(mn[q], __shfl_xor(mn[q], 32, 64));
    sS[q] += __shfl_xor(sS[q], 16, 64);
    sS[q] += __shfl_xor(sS[q], 32, 64);
    sQ[q] += __shfl_xor(sQ[q], 16, 64);
    sQ[q] += __shfl_xor(sQ[q], 32, 64);
  }
  int w = tid >> 6;
  float* redS = bS;          // alias — bS dead after k-loop
  float* redQ = bS + 1024;
  __syncthreads();           // all k-loop bS reads complete
  // pass 1: BN2 stats
  if ((tid & 63) < 16) {
    #pragma unroll
    for (int q4 = 0; q4 < 4; q4++)
      #pragma unroll
      for (int cc = 0; cc < 4; cc++) {
        redS[w*256 + q4*64 + tx*4 + cc] = sS[q4*4+cc];
        redQ[w*256 + q4*64 + tx*4 + cc] = sQ[q4*4+cc];
      }
  }
  __syncthreads();
  float ts = redS[tid]+redS[256+tid]+redS[512+tid]+redS[768+tid];
  float tq = redQ[tid]+redQ[256+tid]+redQ[512+tid]+redQ[768+tid];
  int row = blockIdx.x & (NSH - 1);
  atomicAdd(&stats[row*1024 + 512 + tid], ts);
  atomicAdd(&stats[row*1024 + 768 + tid], tq);
  // pass 2: pooled max/min
  __syncthreads();
  if ((tid & 63) < 16) {
    #pragma unroll
    for (int q4 = 0; q4 < 4; q4++)
      #pragma unroll
      for (int cc = 0; cc < 4; cc++) {
        redS[w*256 + q4*64 + tx*4 + cc] = mx[q4*4+cc];
        redQ[w*256 + q4*64 + tx*4 + cc] = mn[q4*4+cc];
      }
  }
  __syncthreads();
  float mxc = fmaxf(fmaxf(redS[tid], redS[256+tid]), fmaxf(redS[512+tid], redS[768+tid]));
  float mnc = fminf(fminf(redQ[tid], redQ[256+tid]), fminf(redQ[512+tid], redQ[768+tid]));
  int b  = blockIdx.x >> 8;               // 256 blocks per batch
  int sh = blockIdx.x & (PSH - 1);
  atomicMax((int*)&pmaxs[((size_t)sh*BB + b)*DD + tid], __float_as_int(mxc));
  atomicMin((int*)&pmins[((size_t)sh*BB + b)*DD + tid], __float_as_int(mnc));
}

// ---------------- final: BN2 on pooled max/min, two 256x256 linears, l2norm
__global__ __launch_bounds__(256) void finalk(const float* __restrict__ pmaxs, const float* __restrict__ pmins,
    const float* __restrict__ stats, const float* __restrict__ g2, const float* __restrict__ be2,
    const float* __restrict__ W1, const float* __restrict__ b1,
    const float* __restrict__ W2, const float* __restrict__ b2,
    float* __restrict__ out)
{
  __shared__ float pl[8][256];
  __shared__ float hl[8][256];
  __shared__ float nrm[8];
  int c = threadIdx.x;
  const float inv = 1.f / (float)NEDGE;
  float sm = 0.f, sq2 = 0.f;
  #pragma unroll 1
  for (int r = 0; r < NSH; r++) {
    sm  += stats[r*1024 + 512 + c];
    sq2 += stats[r*1024 + 768 + c];
  }
  float m = sm * inv;
  float var = sq2*inv - m*m;
  float s2 = g2[c] / sqrtf(var + BN_EPS);
  float t2 = be2[c] - m*s2;
  #pragma unroll
  for (int b = 0; b < 8; b++) {
    float mx = -3.4e38f, mn = 3.4e38f;
    #pragma unroll 1
    for (int s = 0; s < PSH; s++) {
      mx = fmaxf(mx, pmaxs[((size_t)s*BB + b)*DD + c]);
      mn = fminf(mn, pmins[((size_t)s*BB + b)*DD + c]);
    }
    pl[b][c] = (s2 >= 0.f) ? s2*mx + t2 : s2*mn + t2;
  }
  __syncthreads();
  float h[8];
  #pragma unroll
  for (int b = 0; b < 8; b++) h[b] = b1[c];
  for (int k = 0; k < 256; k++) {
    float w = W1[k*256 + c];
    #pragma unroll
    for (int b = 0; b < 8; b++) h[b] += pl[b][k]*w;
  }
  __syncthreads();
  #pragma unroll
  for (int b = 0; b < 8; b++) hl[b][c] = fmaxf(h[b], 0.f);
  __syncthreads();
  float o[8];
  #pragma unroll
  for (int b = 0; b < 8; b++) o[b] = b2[c];
  for (int k = 0; k < 256; k++) {
    float w = W2[k*256 + c];
    #pragma unroll
    for (int b = 0; b < 8; b++) o[b] += hl[b][k]*w;
  }
  __syncthreads();
  #pragma unroll
  for (int b = 0; b < 8; b++) pl[b][c] = fmaxf(o[b], 0.f);
  __syncthreads();
  if (c < 8) {
    float s = 0.f;
    for (int k = 0; k < 256; k++) { float vv = pl[c][k]; s += vv*vv; }
    nrm[c] = fmaxf(sqrtf(s), 1e-12f);
  }
  __syncthreads();
  #pragma unroll
  for (int b = 0; b < 8; b++) out[b*256 + c] = pl[b][c] / nrm[b];
}

extern "C" void kernel_launch(void* const* d_in, const int* in_sizes, int n_in,
                              void* d_out, int out_size, void* d_ws, size_t ws_size,
                              hipStream_t stream) {
  (void)in_sizes; (void)n_in; (void)out_size; (void)ws_size;
  const int*   cls       = (const int*)  d_in[0];
  const float* colors    = (const float*)d_in[1];
  const float* positions = (const float*)d_in[2];
  const float* ctab      = (const float*)d_in[3];
  const float* pW1 = (const float*)d_in[4];
  const float* pb1 = (const float*)d_in[5];
  const float* pW2 = (const float*)d_in[6];
  const float* pb2 = (const float*)d_in[7];
  const float* cW1 = (const float*)d_in[8];
  const float* cb1 = (const float*)d_in[9];
  const float* cW2 = (const float*)d_in[10];
  const float* cb2 = (const float*)d_in[11];
  const float* mW  = (const float*)d_in[12];
  const float* mb  = (const float*)d_in[13];
  const float* gW1 = (const float*)d_in[14];
  const float* gb1 = (const float*)d_in[15];
  const float* gg1 = (const float*)d_in[16];
  const float* gbe1= (const float*)d_in[17];
  const float* gW2 = (const float*)d_in[18];
  const float* gb2 = (const float*)d_in[19];
  const float* gg2 = (const float*)d_in[20];
  const float* gbe2= (const float*)d_in[21];
  const float* lW1 = (const float*)d_in[22];
  const float* lb1 = (const float*)d_in[23];
  const float* lW2 = (const float*)d_in[24];
  const float* lb2 = (const float*)d_in[25];
  float* out = (float*)d_out;

  float* wsf   = (float*)d_ws;
  float* x     = wsf + OFF_X;
  float* feat  = wsf + OFF_FEAT;
  float* sq    = wsf + OFF_SQ;
  int*   idxg  = (int*)(wsf + OFF_IDX);
  float* u     = wsf + OFF_U;
  float* v     = wsf + OFF_V;
  float* Wu    = wsf + OFF_WU;
  float* W2p   = wsf + OFF_W2P;
  float* biasp = wsf + OFF_BIASP;
  float* stats = wsf + OFF_STATS;
  float* pmaxs = wsf + OFF_PMAXS;
  float* pmins = wsf + OFF_PMINS;
  // partial kNN buffers overlay feat (dead after the merge GEMM): 32 entries/point
  float* pdg   = feat;
  int*   pjg   = (int*)(feat + (size_t)NPTS*32);

  // stats + pmaxs + sq are contiguous -> one zero memset
  hipMemsetAsync(stats, 0, (NSH*1024 + PSH*BB*DD + NPTS)*sizeof(float), stream);
  hipMemsetAsync(pmins, 0x7f, PSH*BB*DD*sizeof(float), stream);   // ~3.39e38f

  featurize<<<NPTS/4, 256, 0, stream>>>(cls, colors, positions, ctab,
                                        pW1, pb1, pW2, pb2, cW1, cb1, cW2, cb2, feat);
  gemm64<768, true, true, true><<<dim3(NPTS/64, 4), 256, 0, stream>>>(feat, mW, mb, x, sq);
  prep_wu<<<DD*DD/256, 256, 0, stream>>>(gW1, Wu);
  knnk<<<BB*32*4, 256, 0, stream>>>(x, sq, pdg, pjg);
  knnmerge<<<NPTS/256, 256, 0, stream>>>(pdg, pjg, idxg);
  gemmuv<<<dim3(NPTS/64, 4), 256, 0, stream>>>(x, Wu, gW1 + DD*DD, u, v);
  bn1stats<<<NPTS/16, 256, 0, stream>>>(u, v, idxg, gb1, stats);
  prep2<<<1, 256, 0, stream>>>(stats, gg1, gbe1, gW2, gb2, W2p, biasp);
  edgek<<<NEDGE/64, 256, 0, stream>>>(u, v, idxg, gb1, W2p, biasp, pmaxs, pmins, stats);
  finalk<<<1, 256, 0, stream>>>(pmaxs, pmins, stats, gg2, gbe2, lW1, lb1, lW2, lb2, out);
}

// Round 12
// 941.644 us; speedup vs baseline: 1.0037x; 1.0037x over previous
//
#include <hip/hip_runtime.h>
#include <math.h>

#define BB 8
#define NN 2048
#define DD 256
#define KNN 8
#define NPTS (BB*NN)        // 16384
#define NEDGE (NPTS*KNN)    // 131072
#define BN_EPS 1e-5f
#define NSH 64              // shadow copies for BN stats accumulation
#define PSH 32              // shadow copies for pooled max/min

// ---- workspace layout (float offsets) ----
// stats+pmaxs+sq contiguous -> single zero memset; pmins separate 0x7f memset.
#define OFF_X      0
#define OFF_FEAT   (OFF_X + NPTS*DD)
#define OFF_STATS  (OFF_FEAT + NPTS*3*DD)     // NSH x 1024
#define OFF_PMAXS  (OFF_STATS + NSH*1024)     // PSH x BB x 256
#define OFF_SQ     (OFF_PMAXS + PSH*BB*DD)    // NPTS
#define OFF_PMINS  (OFF_SQ + NPTS)            // PSH x BB x 256
#define OFF_IDX    (OFF_PMINS + PSH*BB*DD)
#define OFF_U      (OFF_IDX + NEDGE)
#define OFF_V      (OFF_U + NPTS*DD)
#define OFF_W2P    (OFF_V + NPTS*DD)
#define OFF_BIASP  (OFF_W2P + DD*DD)

// async global->LDS, 16B per lane; lbase must be wave-uniform, dest = lbase + lane*16B
__device__ __forceinline__ void gload_lds16(const float* g, float* lbase) {
#if defined(__has_builtin) && __has_builtin(__builtin_amdgcn_global_load_lds)
  __builtin_amdgcn_global_load_lds(
      (const __attribute__((address_space(1))) void*)(g),
      (__attribute__((address_space(3))) void*)(lbase),
      16, 0, 0);
#else
  int lane = threadIdx.x & 63;
  *(float4*)(lbase + lane*4) = *(const float4*)g;
#endif
}

// ---------------- per-point features: wave-per-point, 4 points/block
__global__ __launch_bounds__(256) void featurize(
    const int* __restrict__ cls, const float* __restrict__ colors, const float* __restrict__ positions,
    const float* __restrict__ ctab,
    const float* __restrict__ pW1, const float* __restrict__ pb1, const float* __restrict__ pW2, const float* __restrict__ pb2,
    const float* __restrict__ cW1, const float* __restrict__ cb1, const float* __restrict__ cW2, const float* __restrict__ cb2,
    float* __restrict__ feat)
{
  __shared__ float wbuf[4][64];   // per-wave: [0:32) colh, [32:64) posh
  int tid = threadIdx.x;
  int wv = tid >> 6, lane = tid & 63;
  int p = blockIdx.x*4 + wv;
  if (lane < 32) {
    float c0 = colors[p*3+0], c1 = colors[p*3+1], c2 = colors[p*3+2];
    wbuf[wv][lane] = fmaxf(c0*cW1[lane] + c1*cW1[32+lane] + c2*cW1[64+lane] + cb1[lane], 0.f);
  } else {
    int l = lane - 32;
    float q0 = positions[p*3+0], q1 = positions[p*3+1], q2 = positions[p*3+2];
    wbuf[wv][32+l] = fmaxf(q0*pW1[l] + q1*pW1[32+l] + q2*pW1[64+l] + pb1[l], 0.f);
  }
  __syncthreads();
  int c = lane*4;
  float4 ce4 = *(const float4*)&ctab[(size_t)cls[p]*DD + c];
  float4 col4 = *(const float4*)&cb2[c];
  float4 pos4 = *(const float4*)&pb2[c];
  #pragma unroll
  for (int k = 0; k < 32; k++) {
    float ch = wbuf[wv][k], ph = wbuf[wv][32+k];
    float4 cw = *(const float4*)&cW2[k*DD + c];
    float4 pw = *(const float4*)&pW2[k*DD + c];
    col4.x += ch*cw.x; col4.y += ch*cw.y; col4.z += ch*cw.z; col4.w += ch*cw.w;
    pos4.x += ph*pw.x; pos4.y += ph*pw.y; pos4.z += ph*pw.z; pos4.w += ph*pw.w;
  }
  col4.x = fmaxf(col4.x, 0.f); col4.y = fmaxf(col4.y, 0.f);
  col4.z = fmaxf(col4.z, 0.f); col4.w = fmaxf(col4.w, 0.f);
  pos4.x = fmaxf(pos4.x, 0.f); pos4.y = fmaxf(pos4.y, 0.f);
  pos4.z = fmaxf(pos4.z, 0.f); pos4.w = fmaxf(pos4.w, 0.f);
  float sce  = ce4.x*ce4.x + ce4.y*ce4.y + ce4.z*ce4.z + ce4.w*ce4.w;
  float scol = col4.x*col4.x + col4.y*col4.y + col4.z*col4.z + col4.w*col4.w;
  float spos = pos4.x*pos4.x + pos4.y*pos4.y + pos4.z*pos4.z + pos4.w*pos4.w;
  #pragma unroll
  for (int m = 1; m <= 32; m <<= 1) {
    sce  += __shfl_xor(sce,  m, 64);
    scol += __shfl_xor(scol, m, 64);
    spos += __shfl_xor(spos, m, 64);
  }
  float ice = 1.f / fmaxf(sqrtf(sce),  1e-12f);
  float icl = 1.f / fmaxf(sqrtf(scol), 1e-12f);
  float ips = 1.f / fmaxf(sqrtf(spos), 1e-12f);
  float* fp = feat + (size_t)p*768;
  *(float4*)&fp[c]       = make_float4(ce4.x*ice,  ce4.y*ice,  ce4.z*ice,  ce4.w*ice);
  *(float4*)&fp[256 + c] = make_float4(col4.x*icl, col4.y*icl, col4.z*icl, col4.w*icl);
  *(float4*)&fp[512 + c] = make_float4(pos4.x*ips, pos4.y*ips, pos4.z*ips, pos4.w*ips);
}

// ---------------- generic 64x64-tile GEMM: C[M,256] = act(A[M,KD] @ W[KD,256] (+bias))
// Optional fused row sum-of-squares (atomicAdd into sq, 4 contenders/row).
template<int KD, bool RELU, bool HASBIAS, bool SQOUT>
__global__ __launch_bounds__(256) void gemm64(
    const float* __restrict__ A, const float* __restrict__ W, const float* __restrict__ bias,
    float* __restrict__ C, float* __restrict__ sqo)
{
  __shared__ float aT[32][68];
  __shared__ float bS[32*64];
  int tid = threadIdx.x;
  int tx = tid & 15, ty = tid >> 4;
  int rowbase = blockIdx.x * 64;
  int colbase = blockIdx.y * 64;
  int sr = tid >> 2, sk = (tid & 3) * 8;
  int lane = tid & 63, wv = tid >> 6;
  float acc[4][4] = {};
  for (int kc = 0; kc < KD; kc += 32) {
    const float* ap = A + (size_t)(rowbase + sr)*KD + kc + sk;
    float4 a0 = *(const float4*)ap;
    float4 a1 = *(const float4*)(ap + 4);
    __syncthreads();
    #pragma unroll
    for (int r = 0; r < 2; r++) {
      int R0 = r*16 + wv*4;
      gload_lds16(W + (size_t)(kc + R0 + (lane >> 4))*DD + colbase + (lane & 15)*4,
                  &bS[R0*64]);
    }
    aT[sk+0][sr]=a0.x; aT[sk+1][sr]=a0.y; aT[sk+2][sr]=a0.z; aT[sk+3][sr]=a0.w;
    aT[sk+4][sr]=a1.x; aT[sk+5][sr]=a1.y; aT[sk+6][sr]=a1.z; aT[sk+7][sr]=a1.w;
    __syncthreads();
    #pragma unroll
    for (int k = 0; k < 32; k++) {
      float4 av = *(const float4*)&aT[k][ty*4];
      float4 bv = *(const float4*)&bS[k*64 + tx*4];
      float a_[4] = {av.x, av.y, av.z, av.w};
      float b_[4] = {bv.x, bv.y, bv.z, bv.w};
      #pragma unroll
      for (int rr = 0; rr < 4; rr++)
        #pragma unroll
        for (int cc = 0; cc < 4; cc++)
          acc[rr][cc] += a_[rr]*b_[cc];
    }
  }
  float sqp[4];
  #pragma unroll
  for (int rr = 0; rr < 4; rr++) {
    int row = rowbase + ty*4 + rr;
    float o[4];
    #pragma unroll
    for (int cc = 0; cc < 4; cc++) {
      float v = acc[rr][cc];
      if (HASBIAS) v += bias[colbase + tx*4 + cc];
      if (RELU) v = fmaxf(v, 0.f);
      o[cc] = v;
    }
    if (SQOUT) sqp[rr] = o[0]*o[0] + o[1]*o[1] + o[2]*o[2] + o[3]*o[3];
    *(float4*)&C[(size_t)row*DD + colbase + tx*4] = make_float4(o[0],o[1],o[2],o[3]);
  }
  if (SQOUT) {
    #pragma unroll
    for (int rr = 0; rr < 4; rr++) {
      #pragma unroll
      for (int m = 1; m <= 8; m <<= 1) sqp[rr] += __shfl_xor(sqp[rr], m, 64);
    }
    if (tx == 0) {
      #pragma unroll
      for (int rr = 0; rr < 4; rr++)
        atomicAdd(&sqo[rowbase + ty*4 + rr], sqp[rr]);
    }
  }
}

// ---------------- fused u/v GEMM with inline Wu = W1top - W1bot (prep_wu folded in)
__global__ __launch_bounds__(256) void gemmuv(
    const float* __restrict__ A, const float* __restrict__ gW1,
    float* __restrict__ U, float* __restrict__ V)
{
  __shared__ float aT[32][68];
  __shared__ float bU[32][68];
  __shared__ float bV[32][68];
  int tid = threadIdx.x;
  int tx = tid & 15, ty = tid >> 4;
  int rowbase = blockIdx.x * 64;
  int colbase = blockIdx.y * 64;
  int sr = tid >> 2, sk = (tid & 3) * 8;
  float accU[4][4] = {}, accV[4][4] = {};
  for (int kc = 0; kc < DD; kc += 32) {
    const float* ap = A + (size_t)(rowbase + sr)*DD + kc + sk;
    float4 a0 = *(const float4*)ap;
    float4 a1 = *(const float4*)(ap + 4);
    const float* wt = gW1 + (size_t)(kc + ty)*DD + colbase + tx*4;
    const float* wb = wt + (size_t)DD*DD;
    float4 t0 = *(const float4*)wt;
    float4 t1 = *(const float4*)(wt + (size_t)16*DD);
    float4 o0 = *(const float4*)wb;
    float4 o1 = *(const float4*)(wb + (size_t)16*DD);
    __syncthreads();
    aT[sk+0][sr]=a0.x; aT[sk+1][sr]=a0.y; aT[sk+2][sr]=a0.z; aT[sk+3][sr]=a0.w;
    aT[sk+4][sr]=a1.x; aT[sk+5][sr]=a1.y; aT[sk+6][sr]=a1.z; aT[sk+7][sr]=a1.w;
    *(float4*)&bU[ty][tx*4]      = make_float4(t0.x-o0.x, t0.y-o0.y, t0.z-o0.z, t0.w-o0.w);
    *(float4*)&bU[ty + 16][tx*4] = make_float4(t1.x-o1.x, t1.y-o1.y, t1.z-o1.z, t1.w-o1.w);
    *(float4*)&bV[ty][tx*4]      = o0;
    *(float4*)&bV[ty + 16][tx*4] = o1;
    __syncthreads();
    #pragma unroll
    for (int k = 0; k < 32; k++) {
      float4 av = *(const float4*)&aT[k][ty*4];
      float4 bu = *(const float4*)&bU[k][tx*4];
      float4 bv = *(const float4*)&bV[k][tx*4];
      float a_[4] = {av.x, av.y, av.z, av.w};
      float u_[4] = {bu.x, bu.y, bu.z, bu.w};
      float v_[4] = {bv.x, bv.y, bv.z, bv.w};
      #pragma unroll
      for (int rr = 0; rr < 4; rr++)
        #pragma unroll
        for (int cc = 0; cc < 4; cc++) {
          accU[rr][cc] += a_[rr]*u_[cc];
          accV[rr][cc] += a_[rr]*v_[cc];
        }
    }
  }
  #pragma unroll
  for (int rr = 0; rr < 4; rr++) {
    int row = rowbase + ty*4 + rr;
    *(float4*)&U[(size_t)row*DD + colbase + tx*4] =
        make_float4(accU[rr][0], accU[rr][1], accU[rr][2], accU[rr][3]);
    *(float4*)&V[(size_t)row*DD + colbase + tx*4] =
        make_float4(accV[rr][0], accV[rr][1], accV[rr][2], accV[rr][3]);
  }
}

// ---------------- kNN partial: per (batch, 64-row i-tile, j-quarter), keep 8 smallest d
// R10-proven body (dt aliased onto aT/bT, XOR-16 staging swizzle, LDS 17.9 KB).
__global__ __launch_bounds__(256) void knnk(const float* __restrict__ x, const float* __restrict__ sq,
                                            float* __restrict__ pdg, int* __restrict__ pjg)
{
  __shared__ float smem[4480];
  float (*aT)[68] = (float(*)[68])smem;
  float (*bT)[68] = (float(*)[68])(smem + 2176);
  float (*dt)[65] = (float(*)[65])smem;       // aliases aT/bT (dead when dt is live)
  float* sqI = smem + 4352;
  float* sqJ = smem + 4416;
  int tid = threadIdx.x;
  int q  = blockIdx.x & 3;
  int it = (blockIdx.x >> 2) & 31;
  int bb = blockIdx.x >> 7;
  int ibase = it * 64;
  const float* xb  = x  + (size_t)bb*NN*DD;
  const float* sqb = sq + (size_t)bb*NN;
  int tx = tid & 15, ty = tid >> 4;
  int sr = tid >> 2, sk = (tid & 3) * 8;
  int srw = sr ^ ((tid & 1) << 4);   // staging-write swizzle (breaks 4-way bank conflict)
  int selrow = tid & 63, selseg = tid >> 6;
  float bd[8]; int bj[8];
  #pragma unroll
  for (int s = 0; s < 8; s++) { bd[s] = 3.4e38f; bj[s] = 0; }
  if (tid < 64) sqI[tid] = sqb[ibase + tid];
  for (int jt = 0; jt < 8; jt++) {
    int jbase = q*512 + jt*64;
    float acc[4][4] = {};
    for (int kc = 0; kc < DD; kc += 32) {
      const float* ap = xb + (size_t)(ibase + sr)*DD + kc + sk;
      float4 a0 = *(const float4*)ap;
      float4 a1 = *(const float4*)(ap + 4);
      const float* bp = xb + (size_t)(jbase + sr)*DD + kc + sk;
      float4 b0  = *(const float4*)bp;
      float4 b1v = *(const float4*)(bp + 4);
      float sjv = 0.f;
      if (kc == 0 && tid < 64) sjv = sqb[jbase + tid];
      __syncthreads();
      aT[sk+0][srw]=a0.x; aT[sk+1][srw]=a0.y; aT[sk+2][srw]=a0.z; aT[sk+3][srw]=a0.w;
      aT[sk+4][srw]=a1.x; aT[sk+5][srw]=a1.y; aT[sk+6][srw]=a1.z; aT[sk+7][srw]=a1.w;
      bT[sk+0][srw]=b0.x; bT[sk+1][srw]=b0.y; bT[sk+2][srw]=b0.z; bT[sk+3][srw]=b0.w;
      bT[sk+4][srw]=b1v.x; bT[sk+5][srw]=b1v.y; bT[sk+6][srw]=b1v.z; bT[sk+7][srw]=b1v.w;
      if (kc == 0 && tid < 64) sqJ[tid] = sjv;
      __syncthreads();
      #pragma unroll
      for (int k = 0; k < 32; k++) {
        int rsw = ((k >> 3) & 1) << 4;
        float4 av = *(const float4*)&aT[k][(ty*4) ^ rsw];
        float4 bv = *(const float4*)&bT[k][(tx*4) ^ rsw];
        float a_[4] = {av.x, av.y, av.z, av.w};
        float b_[4] = {bv.x, bv.y, bv.z, bv.w};
        #pragma unroll
        for (int rr = 0; rr < 4; rr++)
          #pragma unroll
          for (int cc = 0; cc < 4; cc++)
            acc[rr][cc] += a_[rr]*b_[cc];
      }
    }
    __syncthreads();   // aT/bT reads done before dt (aliased) writes
    #pragma unroll
    for (int rr = 0; rr < 4; rr++)
      #pragma unroll
      for (int cc = 0; cc < 4; cc++)
        dt[ty*4+rr][tx*4+cc] = sqI[ty*4+rr] + sqJ[tx*4+cc] - 2.f*acc[rr][cc];
    __syncthreads();
    int cb = selseg*16;
    #pragma unroll
    for (int s = 0; s < 16; s++) {
      float dv = dt[selrow][cb + s];
      if (dv < bd[7]) {
        bd[7] = dv; bj[7] = jbase + cb + s;
        #pragma unroll
        for (int t = 7; t >= 1; t--) {
          if (bd[t] < bd[t-1]) {
            float td = bd[t]; bd[t] = bd[t-1]; bd[t-1] = td;
            int   tj = bj[t]; bj[t] = bj[t-1]; bj[t-1] = tj;
          }
        }
      }
    }
    __syncthreads();   // dt reads done before next tile's staging (aliased) writes
  }
  // stage per-thread lists in LDS (overlay aT/bT)
  float* pdl = &smem[0];
  int*   pjl = (int*)&smem[2176];
  #pragma unroll
  for (int s = 0; s < 8; s++) {
    pdl[tid*8 + s] = bd[s];
    pjl[tid*8 + s] = bj[s];
  }
  __syncthreads();
  if (tid < 64) {
    float md[8]; int mj[8];
    #pragma unroll
    for (int s = 0; s < 8; s++) { md[s] = 3.4e38f; mj[s] = 0; }
    #pragma unroll 1
    for (int g = 0; g < 4; g++) {
      int base = (g*64 + tid)*8;
      #pragma unroll
      for (int s = 0; s < 8; s++) {
        float dv = pdl[base + s];
        if (dv < md[7]) {
          md[7] = dv; mj[7] = pjl[base + s];
          #pragma unroll
          for (int t = 7; t >= 1; t--) {
            if (md[t] < md[t-1]) {
              float td = md[t]; md[t] = md[t-1]; md[t-1] = td;
              int   tj = mj[t]; mj[t] = mj[t-1]; mj[t-1] = tj;
            }
          }
        }
      }
    }
    size_t gbase = ((size_t)(bb*NN + ibase + tid))*32 + (size_t)q*8;
    #pragma unroll
    for (int s = 0; s < 8; s++) {
      pdg[gbase + s] = md[s];
      pjg[gbase + s] = bb*NN + mj[s];
    }
  }
}

// ---------------- merge 4 quarter-lists per point -> final 8 neighbor indices
__global__ __launch_bounds__(256) void knnmerge(const float* __restrict__ pdg, const int* __restrict__ pjg,
                                                int* __restrict__ idxg)
{
  int p = blockIdx.x*256 + threadIdx.x;
  float md[8]; int mj[8];
  #pragma unroll
  for (int s = 0; s < 8; s++) { md[s] = 3.4e38f; mj[s] = 0; }
  size_t base = (size_t)p*32;
  #pragma unroll 1
  for (int s = 0; s < 32; s++) {
    float dv = pdg[base + s];
    if (dv < md[7]) {
      md[7] = dv; mj[7] = pjg[base + s];
      #pragma unroll
      for (int t = 7; t >= 1; t--) {
        if (md[t] < md[t-1]) {
          float td = md[t]; md[t] = md[t-1]; md[t-1] = td;
          int   tj = mj[t]; mj[t] = mj[t-1]; mj[t-1] = tj;
        }
      }
    }
  }
  #pragma unroll
  for (int s = 0; s < 8; s++) idxg[(size_t)p*8 + s] = mj[s];
}

// ---------------- BN1 stats: h1 = relu(u_i + v_j + b1), shadow-accumulator atomics
__global__ __launch_bounds__(256) void bn1stats(const float* __restrict__ u, const float* __restrict__ v,
    const int* __restrict__ idxg, const float* __restrict__ b1, float* __restrict__ stats)
{
  __shared__ int jL[128];
  int c = threadIdx.x;
  int n0 = blockIdx.x * 16;
  if (c < 128) jL[c] = idxg[(size_t)n0*8 + c];
  __syncthreads();
  float b1c = b1[c];
  float s = 0.f, s2 = 0.f;
  #pragma unroll 1
  for (int n = 0; n < 16; n++) {
    float uc = u[(size_t)(n0 + n)*DD + c];
    #pragma unroll
    for (int e = 0; e < 8; e++) {
      int j = jL[n*8 + e];
      float h = fmaxf(uc + v[(size_t)j*DD + c] + b1c, 0.f);
      s += h; s2 += h*h;
    }
  }
  int row = blockIdx.x & (NSH - 1);
  atomicAdd(&stats[row*1024 + c], s);
  atomicAdd(&stats[row*1024 + 256 + c], s2);
}

// ---------------- fold BN1 into layer-2 weights: W2' = diag(s1) W2 ; bias' = b2 + t1.W2
__global__ __launch_bounds__(256) void prep2(const float* __restrict__ stats, const float* __restrict__ g1,
    const float* __restrict__ be1, const float* __restrict__ gW2, const float* __restrict__ gb2,
    float* __restrict__ W2p, float* __restrict__ biasp)
{
  __shared__ float s1L[256], t1L[256];
  int tid = threadIdx.x;
  const float inv = 1.f / (float)NEDGE;
  float sm = 0.f, sq2 = 0.f;
  #pragma unroll 1
  for (int r = 0; r < NSH; r++) {
    sm  += stats[r*1024 + tid];
    sq2 += stats[r*1024 + 256 + tid];
  }
  float m = sm * inv;
  float var = sq2*inv - m*m;
  float s1 = g1[tid] / sqrtf(var + BN_EPS);
  s1L[tid] = s1; t1L[tid] = be1[tid] - m*s1;
  __syncthreads();
  float bacc = gb2[tid];
  for (int k = 0; k < DD; k++) {
    float w = gW2[k*DD + tid];
    W2p[k*DD + tid] = s1L[k]*w;
    bacc += t1L[k]*w;
  }
  biasp[tid] = bacc;
}

// ---------------- edge GEMM: h2 = relu( relu(u_i+v_j+b1) @ W2' + bias' )
// BK=32 (R10-proven barrier cadence) + column split x2 (64 edges x 128 cols per block):
// LDS 16 KB bS + 8.7 KB aT -> ~25 KB -> 6 blocks/CU. Epilogue aliases dead bS.
__global__ __launch_bounds__(256) void edgek(
    const float* __restrict__ u, const float* __restrict__ v, const int* __restrict__ idxg,
    const float* __restrict__ b1, const float* __restrict__ W2p, const float* __restrict__ biasp,
    float* __restrict__ pmaxs, float* __restrict__ pmins, float* __restrict__ stats)
{
  __shared__ float aT[32][68];
  __shared__ float bS[32*128];    // 16 KB; epilogue reductions alias here
  __shared__ int   jL[64];
  int tid = threadIdx.x;
  int tx = tid & 15, ty = tid >> 4;
  int rowbase = blockIdx.x * 64;
  int colbase = blockIdx.y * 128;
  if (tid < 64) jL[tid] = idxg[rowbase + tid];
  __syncthreads();
  int sr = tid >> 2, sk = (tid & 3) * 8;
  int iu = (rowbase + sr) >> 3;
  int lane = tid & 63, wv = tid >> 6;
  int jv = jL[sr];
  const float* urow = u + (size_t)iu*DD;
  const float* vrow = v + (size_t)jv*DD;
  float acc[4][8] = {};
  for (int kc = 0; kc < DD; kc += 32) {
    float4 u0 = *(const float4*)(urow + kc + sk);
    float4 u1 = *(const float4*)(urow + kc + sk + 4);
    float4 v0 = *(const float4*)(vrow + kc + sk);
    float4 v1 = *(const float4*)(vrow + kc + sk + 4);
    float4 c0 = *(const float4*)&b1[kc + sk];
    float4 c1 = *(const float4*)&b1[kc + sk + 4];
    __syncthreads();
    // DMA: each wave-load stages 2 rows x 128 cols (256 floats)
    #pragma unroll
    for (int rI = 0; rI < 4; rI++) {
      int R = rI*8 + wv*2;
      gload_lds16(W2p + (size_t)(kc + R + (lane >> 5))*DD + colbase + (lane & 31)*4,
                  &bS[R*128]);
    }
    aT[sk+0][sr] = fmaxf(u0.x+v0.x+c0.x, 0.f);
    aT[sk+1][sr] = fmaxf(u0.y+v0.y+c0.y, 0.f);
    aT[sk+2][sr] = fmaxf(u0.z+v0.z+c0.z, 0.f);
    aT[sk+3][sr] = fmaxf(u0.w+v0.w+c0.w, 0.f);
    aT[sk+4][sr] = fmaxf(u1.x+v1.x+c1.x, 0.f);
    aT[sk+5][sr] = fmaxf(u1.y+v1.y+c1.y, 0.f);
    aT[sk+6][sr] = fmaxf(u1.z+v1.z+c1.z, 0.f);
    aT[sk+7][sr] = fmaxf(u1.w+v1.w+c1.w, 0.f);
    __syncthreads();
    #pragma unroll
    for (int k = 0; k < 32; k++) {
      float4 av = *(const float4*)&aT[k][ty*4];
      float a_[4] = {av.x, av.y, av.z, av.w};
      #pragma unroll
      for (int q = 0; q < 2; q++) {
        float4 bv = *(const float4*)&bS[k*128 + q*64 + tx*4];
        float b_[4] = {bv.x, bv.y, bv.z, bv.w};
        #pragma unroll
        for (int rr = 0; rr < 4; rr++)
          #pragma unroll
          for (int cc = 0; cc < 4; cc++)
            acc[rr][q*4+cc] += a_[rr]*b_[cc];
      }
    }
  }
  // epilogue: bias + relu, per-node max/min over K, BN2 sums, pooled max/min
  float mx[8], mn[8], sS[8], sQ[8];
  #pragma unroll
  for (int q = 0; q < 2; q++) {
    #pragma unroll
    for (int cc = 0; cc < 4; cc++) {
      int col = q*64 + tx*4 + cc;
      float bp = biasp[colbase + col];
      int qi = q*4 + cc;
      float h0 = fmaxf(acc[0][qi] + bp, 0.f);
      float h1 = fmaxf(acc[1][qi] + bp, 0.f);
      float h2 = fmaxf(acc[2][qi] + bp, 0.f);
      float h3 = fmaxf(acc[3][qi] + bp, 0.f);
      mx[qi] = fmaxf(fmaxf(h0,h1), fmaxf(h2,h3));
      mn[qi] = fminf(fminf(h0,h1), fminf(h2,h3));
      sS[qi] = h0+h1+h2+h3;
      sQ[qi] = h0*h0+h1*h1+h2*h2+h3*h3;
    }
  }
  #pragma unroll
  for (int qi = 0; qi < 8; qi++) {
    mx[qi] = fmaxf(mx[qi], __shfl_xor(mx[qi], 16, 64));
    mx[qi] = fmaxf(mx[qi], __shfl_xor(mx[qi], 32, 64));
    mn[qi] = fminf(mn[qi], __shfl_xor(mn[qi], 16, 64));
    mn[qi] = fminf(mn[qi], __shfl_xor(mn[qi], 32, 64));
    sS[qi] += __shfl_xor(sS[qi], 16, 64);
    sS[qi] += __shfl_xor(sS[qi], 32, 64);
    sQ[qi] += __shfl_xor(sQ[qi], 16, 64);
    sQ[qi] += __shfl_xor(sQ[qi], 32, 64);
  }
  float* redS = bS;            // 4x128
  float* redQ = bS + 512;      // 4x128
  float* redM = bS + 1024;     // 4x128
  float* redN = bS + 1536;     // 4x128
  __syncthreads();             // all k-loop bS reads complete
  if ((tid & 63) < 16) {
    #pragma unroll
    for (int q = 0; q < 2; q++)
      #pragma unroll
      for (int cc = 0; cc < 4; cc++) {
        int col = q*64 + tx*4 + cc;
        redS[wv*128 + col] = sS[q*4+cc];
        redQ[wv*128 + col] = sQ[q*4+cc];
        redM[wv*128 + col] = mx[q*4+cc];
        redN[wv*128 + col] = mn[q*4+cc];
      }
  }
  __syncthreads();
  if (tid < 128) {
    float ts = redS[tid]+redS[128+tid]+redS[256+tid]+redS[384+tid];
    float tq = redQ[tid]+redQ[128+tid]+redQ[256+tid]+redQ[384+tid];
    float mxc = fmaxf(fmaxf(redM[tid], redM[128+tid]), fmaxf(redM[256+tid], redM[384+tid]));
    float mnc = fminf(fminf(redN[tid], redN[128+tid]), fminf(redN[256+tid], redN[384+tid]));
    int row = blockIdx.x & (NSH - 1);
    atomicAdd(&stats[row*1024 + 512 + colbase + tid], ts);
    atomicAdd(&stats[row*1024 + 768 + colbase + tid], tq);
    int b  = blockIdx.x >> 8;               // 256 x-blocks per batch
    int sh = blockIdx.x & (PSH - 1);
    atomicMax((int*)&pmaxs[((size_t)sh*BB + b)*DD + colbase + tid], __float_as_int(mxc));
    atomicMin((int*)&pmins[((size_t)sh*BB + b)*DD + colbase + tid], __float_as_int(mnc));
  }
}

// ---------------- final: BN2 on pooled max/min, two 256x256 linears, l2norm
__global__ __launch_bounds__(256) void finalk(const float* __restrict__ pmaxs, const float* __restrict__ pmins,
    const float* __restrict__ stats, const float* __restrict__ g2, const float* __restrict__ be2,
    const float* __restrict__ W1, const float* __restrict__ b1,
    const float* __restrict__ W2, const float* __restrict__ b2,
    float* __restrict__ out)
{
  __shared__ float pl[8][256];
  __shared__ float hl[8][256];
  __shared__ float nrm[8];
  int c = threadIdx.x;
  const float inv = 1.f / (float)NEDGE;
  float sm = 0.f, sq2 = 0.f;
  #pragma unroll 1
  for (int r = 0; r < NSH; r++) {
    sm  += stats[r*1024 + 512 + c];
    sq2 += stats[r*1024 + 768 + c];
  }
  float m = sm * inv;
  float var = sq2*inv - m*m;
  float s2 = g2[c] / sqrtf(var + BN_EPS);
  float t2 = be2[c] - m*s2;
  #pragma unroll
  for (int b = 0; b < 8; b++) {
    float mx = -3.4e38f, mn = 3.4e38f;
    #pragma unroll 1
    for (int s = 0; s < PSH; s++) {
      mx = fmaxf(mx, pmaxs[((size_t)s*BB + b)*DD + c]);
      mn = fminf(mn, pmins[((size_t)s*BB + b)*DD + c]);
    }
    pl[b][c] = (s2 >= 0.f) ? s2*mx + t2 : s2*mn + t2;
  }
  __syncthreads();
  float h[8];
  #pragma unroll
  for (int b = 0; b < 8; b++) h[b] = b1[c];
  for (int k = 0; k < 256; k++) {
    float w = W1[k*256 + c];
    #pragma unroll
    for (int b = 0; b < 8; b++) h[b] += pl[b][k]*w;
  }
  __syncthreads();
  #pragma unroll
  for (int b = 0; b < 8; b++) hl[b][c] = fmaxf(h[b], 0.f);
  __syncthreads();
  float o[8];
  #pragma unroll
  for (int b = 0; b < 8; b++) o[b] = b2[c];
  for (int k = 0; k < 256; k++) {
    float w = W2[k*256 + c];
    #pragma unroll
    for (int b = 0; b < 8; b++) o[b] += hl[b][k]*w;
  }
  __syncthreads();
  #pragma unroll
  for (int b = 0; b < 8; b++) pl[b][c] = fmaxf(o[b], 0.f);
  __syncthreads();
  if (c < 8) {
    float s = 0.f;
    for (int k = 0; k < 256; k++) { float vv = pl[c][k]; s += vv*vv; }
    nrm[c] = fmaxf(sqrtf(s), 1e-12f);
  }
  __syncthreads();
  #pragma unroll
  for (int b = 0; b < 8; b++) out[b*256 + c] = pl[b][c] / nrm[b];
}

extern "C" void kernel_launch(void* const* d_in, const int* in_sizes, int n_in,
                              void* d_out, int out_size, void* d_ws, size_t ws_size,
                              hipStream_t stream) {
  (void)in_sizes; (void)n_in; (void)out_size; (void)ws_size;
  const int*   cls       = (const int*)  d_in[0];
  const float* colors    = (const float*)d_in[1];
  const float* positions = (const float*)d_in[2];
  const float* ctab      = (const float*)d_in[3];
  const float* pW1 = (const float*)d_in[4];
  const float* pb1 = (const float*)d_in[5];
  const float* pW2 = (const float*)d_in[6];
  const float* pb2 = (const float*)d_in[7];
  const float* cW1 = (const float*)d_in[8];
  const float* cb1 = (const float*)d_in[9];
  const float* cW2 = (const float*)d_in[10];
  const float* cb2 = (const float*)d_in[11];
  const float* mW  = (const float*)d_in[12];
  const float* mb  = (const float*)d_in[13];
  const float* gW1 = (const float*)d_in[14];
  const float* gb1 = (const float*)d_in[15];
  const float* gg1 = (const float*)d_in[16];
  const float* gbe1= (const float*)d_in[17];
  const float* gW2 = (const float*)d_in[18];
  const float* gb2 = (const float*)d_in[19];
  const float* gg2 = (const float*)d_in[20];
  const float* gbe2= (const float*)d_in[21];
  const float* lW1 = (const float*)d_in[22];
  const float* lb1 = (const float*)d_in[23];
  const float* lW2 = (const float*)d_in[24];
  const float* lb2 = (const float*)d_in[25];
  float* out = (float*)d_out;

  float* wsf   = (float*)d_ws;
  float* x     = wsf + OFF_X;
  float* feat  = wsf + OFF_FEAT;
  float* sq    = wsf + OFF_SQ;
  int*   idxg  = (int*)(wsf + OFF_IDX);
  float* u     = wsf + OFF_U;
  float* v     = wsf + OFF_V;
  float* W2p   = wsf + OFF_W2P;
  float* biasp = wsf + OFF_BIASP;
  float* stats = wsf + OFF_STATS;
  float* pmaxs = wsf + OFF_PMAXS;
  float* pmins = wsf + OFF_PMINS;
  // partial kNN buffers overlay feat (dead after the merge GEMM): 32 entries/point
  float* pdg   = feat;
  int*   pjg   = (int*)(feat + (size_t)NPTS*32);

  // stats + pmaxs + sq are contiguous -> one zero memset
  hipMemsetAsync(stats, 0, (NSH*1024 + PSH*BB*DD + NPTS)*sizeof(float), stream);
  hipMemsetAsync(pmins, 0x7f, PSH*BB*DD*sizeof(float), stream);   // ~3.39e38f

  featurize<<<NPTS/4, 256, 0, stream>>>(cls, colors, positions, ctab,
                                        pW1, pb1, pW2, pb2, cW1, cb1, cW2, cb2, feat);
  gemm64<768, true, true, true><<<dim3(NPTS/64, 4), 256, 0, stream>>>(feat, mW, mb, x, sq);
  knnk<<<BB*32*4, 256, 0, stream>>>(x, sq, pdg, pjg);
  knnmerge<<<NPTS/256, 256, 0, stream>>>(pdg, pjg, idxg);
  gemmuv<<<dim3(NPTS/64, 4), 256, 0, stream>>>(x, gW1, u, v);
  bn1stats<<<NPTS/16, 256, 0, stream>>>(u, v, idxg, gb1, stats);
  prep2<<<1, 256, 0, stream>>>(stats, gg1, gbe1, gW2, gb2, W2p, biasp);
  edgek<<<dim3(NEDGE/64, 2), 256, 0, stream>>>(u, v, idxg, gb1, W2p, biasp, pmaxs, pmins, stats);
  finalk<<<1, 256, 0, stream>>>(pmaxs, pmins, stats, gg2, gbe2, lW1, lb1, lW2, lb2, out);
}

// Round 13
// 872.254 us; speedup vs baseline: 1.0835x; 1.0796x over previous
//
#include <hip/hip_runtime.h>
#include <math.h>

#define BB 8
#define NN 2048
#define DD 256
#define KNN 8
#define NPTS (BB*NN)        // 16384
#define NEDGE (NPTS*KNN)    // 131072
#define BN_EPS 1e-5f
#define NSH 64              // shadow copies for BN stats accumulation
#define PSH 32              // shadow copies for pooled max/min

// ---- workspace layout (float offsets) ----
#define OFF_X      0
#define OFF_FEAT   (OFF_X + NPTS*DD)
#define OFF_STATS  (OFF_FEAT + NPTS*3*DD)     // NSH x 1024
#define OFF_PMAXS  (OFF_STATS + NSH*1024)     // PSH x BB x 256
#define OFF_SQ     (OFF_PMAXS + PSH*BB*DD)    // NPTS
#define OFF_PMINS  (OFF_SQ + NPTS)            // PSH x BB x 256
#define OFF_IDX    (OFF_PMINS + PSH*BB*DD)
#define OFF_U      (OFF_IDX + NEDGE)
#define OFF_V      (OFF_U + NPTS*DD)
#define OFF_W2BF   (OFF_V + NPTS*DD)          // 256x256 ushort (32768 floats reserved)
#define OFF_BIASP  (OFF_W2BF + 32768)

typedef __attribute__((ext_vector_type(8))) short bf16x8;
typedef __attribute__((ext_vector_type(4))) float f32x4;

__device__ __forceinline__ unsigned short f2bf(float f) {
  unsigned int u = __float_as_uint(f);
  u += 0x7FFF + ((u >> 16) & 1);   // round to nearest even
  return (unsigned short)(u >> 16);
}

// async global->LDS, 16B per lane; lbase must be wave-uniform, dest = lbase + lane*16B
__device__ __forceinline__ void gload_lds16(const float* g, float* lbase) {
#if defined(__has_builtin) && __has_builtin(__builtin_amdgcn_global_load_lds)
  __builtin_amdgcn_global_load_lds(
      (const __attribute__((address_space(1))) void*)(g),
      (__attribute__((address_space(3))) void*)(lbase),
      16, 0, 0);
#else
  int lane = threadIdx.x & 63;
  *(float4*)(lbase + lane*4) = *(const float4*)g;
#endif
}

// ---------------- per-point features: wave-per-point, 4 points/block
__global__ __launch_bounds__(256) void featurize(
    const int* __restrict__ cls, const float* __restrict__ colors, const float* __restrict__ positions,
    const float* __restrict__ ctab,
    const float* __restrict__ pW1, const float* __restrict__ pb1, const float* __restrict__ pW2, const float* __restrict__ pb2,
    const float* __restrict__ cW1, const float* __restrict__ cb1, const float* __restrict__ cW2, const float* __restrict__ cb2,
    float* __restrict__ feat)
{
  __shared__ float wbuf[4][64];
  int tid = threadIdx.x;
  int wv = tid >> 6, lane = tid & 63;
  int p = blockIdx.x*4 + wv;
  if (lane < 32) {
    float c0 = colors[p*3+0], c1 = colors[p*3+1], c2 = colors[p*3+2];
    wbuf[wv][lane] = fmaxf(c0*cW1[lane] + c1*cW1[32+lane] + c2*cW1[64+lane] + cb1[lane], 0.f);
  } else {
    int l = lane - 32;
    float q0 = positions[p*3+0], q1 = positions[p*3+1], q2 = positions[p*3+2];
    wbuf[wv][32+l] = fmaxf(q0*pW1[l] + q1*pW1[32+l] + q2*pW1[64+l] + pb1[l], 0.f);
  }
  __syncthreads();
  int c = lane*4;
  float4 ce4 = *(const float4*)&ctab[(size_t)cls[p]*DD + c];
  float4 col4 = *(const float4*)&cb2[c];
  float4 pos4 = *(const float4*)&pb2[c];
  #pragma unroll
  for (int k = 0; k < 32; k++) {
    float ch = wbuf[wv][k], ph = wbuf[wv][32+k];
    float4 cw = *(const float4*)&cW2[k*DD + c];
    float4 pw = *(const float4*)&pW2[k*DD + c];
    col4.x += ch*cw.x; col4.y += ch*cw.y; col4.z += ch*cw.z; col4.w += ch*cw.w;
    pos4.x += ph*pw.x; pos4.y += ph*pw.y; pos4.z += ph*pw.z; pos4.w += ph*pw.w;
  }
  col4.x = fmaxf(col4.x, 0.f); col4.y = fmaxf(col4.y, 0.f);
  col4.z = fmaxf(col4.z, 0.f); col4.w = fmaxf(col4.w, 0.f);
  pos4.x = fmaxf(pos4.x, 0.f); pos4.y = fmaxf(pos4.y, 0.f);
  pos4.z = fmaxf(pos4.z, 0.f); pos4.w = fmaxf(pos4.w, 0.f);
  float sce  = ce4.x*ce4.x + ce4.y*ce4.y + ce4.z*ce4.z + ce4.w*ce4.w;
  float scol = col4.x*col4.x + col4.y*col4.y + col4.z*col4.z + col4.w*col4.w;
  float spos = pos4.x*pos4.x + pos4.y*pos4.y + pos4.z*pos4.z + pos4.w*pos4.w;
  #pragma unroll
  for (int m = 1; m <= 32; m <<= 1) {
    sce  += __shfl_xor(sce,  m, 64);
    scol += __shfl_xor(scol, m, 64);
    spos += __shfl_xor(spos, m, 64);
  }
  float ice = 1.f / fmaxf(sqrtf(sce),  1e-12f);
  float icl = 1.f / fmaxf(sqrtf(scol), 1e-12f);
  float ips = 1.f / fmaxf(sqrtf(spos), 1e-12f);
  float* fp = feat + (size_t)p*768;
  *(float4*)&fp[c]       = make_float4(ce4.x*ice,  ce4.y*ice,  ce4.z*ice,  ce4.w*ice);
  *(float4*)&fp[256 + c] = make_float4(col4.x*icl, col4.y*icl, col4.z*icl, col4.w*icl);
  *(float4*)&fp[512 + c] = make_float4(pos4.x*ips, pos4.y*ips, pos4.z*ips, pos4.w*ips);
}

// ---------------- generic 64x64-tile GEMM (fp32, unchanged)
template<int KD, bool RELU, bool HASBIAS, bool SQOUT>
__global__ __launch_bounds__(256) void gemm64(
    const float* __restrict__ A, const float* __restrict__ W, const float* __restrict__ bias,
    float* __restrict__ C, float* __restrict__ sqo)
{
  __shared__ float aT[32][68];
  __shared__ float bS[32*64];
  int tid = threadIdx.x;
  int tx = tid & 15, ty = tid >> 4;
  int rowbase = blockIdx.x * 64;
  int colbase = blockIdx.y * 64;
  int sr = tid >> 2, sk = (tid & 3) * 8;
  int lane = tid & 63, wv = tid >> 6;
  float acc[4][4] = {};
  for (int kc = 0; kc < KD; kc += 32) {
    const float* ap = A + (size_t)(rowbase + sr)*KD + kc + sk;
    float4 a0 = *(const float4*)ap;
    float4 a1 = *(const float4*)(ap + 4);
    __syncthreads();
    #pragma unroll
    for (int r = 0; r < 2; r++) {
      int R0 = r*16 + wv*4;
      gload_lds16(W + (size_t)(kc + R0 + (lane >> 4))*DD + colbase + (lane & 15)*4,
                  &bS[R0*64]);
    }
    aT[sk+0][sr]=a0.x; aT[sk+1][sr]=a0.y; aT[sk+2][sr]=a0.z; aT[sk+3][sr]=a0.w;
    aT[sk+4][sr]=a1.x; aT[sk+5][sr]=a1.y; aT[sk+6][sr]=a1.z; aT[sk+7][sr]=a1.w;
    __syncthreads();
    #pragma unroll
    for (int k = 0; k < 32; k++) {
      float4 av = *(const float4*)&aT[k][ty*4];
      float4 bv = *(const float4*)&bS[k*64 + tx*4];
      float a_[4] = {av.x, av.y, av.z, av.w};
      float b_[4] = {bv.x, bv.y, bv.z, bv.w};
      #pragma unroll
      for (int rr = 0; rr < 4; rr++)
        #pragma unroll
        for (int cc = 0; cc < 4; cc++)
          acc[rr][cc] += a_[rr]*b_[cc];
    }
  }
  float sqp[4];
  #pragma unroll
  for (int rr = 0; rr < 4; rr++) {
    int row = rowbase + ty*4 + rr;
    float o[4];
    #pragma unroll
    for (int cc = 0; cc < 4; cc++) {
      float v = acc[rr][cc];
      if (HASBIAS) v += bias[colbase + tx*4 + cc];
      if (RELU) v = fmaxf(v, 0.f);
      o[cc] = v;
    }
    if (SQOUT) sqp[rr] = o[0]*o[0] + o[1]*o[1] + o[2]*o[2] + o[3]*o[3];
    *(float4*)&C[(size_t)row*DD + colbase + tx*4] = make_float4(o[0],o[1],o[2],o[3]);
  }
  if (SQOUT) {
    #pragma unroll
    for (int rr = 0; rr < 4; rr++) {
      #pragma unroll
      for (int m = 1; m <= 8; m <<= 1) sqp[rr] += __shfl_xor(sqp[rr], m, 64);
    }
    if (tx == 0) {
      #pragma unroll
      for (int rr = 0; rr < 4; rr++)
        atomicAdd(&sqo[rowbase + ty*4 + rr], sqp[rr]);
    }
  }
}

// ---------------- fused u/v GEMM with inline Wu = W1top - W1bot (fp32, unchanged)
__global__ __launch_bounds__(256) void gemmuv(
    const float* __restrict__ A, const float* __restrict__ gW1,
    float* __restrict__ U, float* __restrict__ V)
{
  __shared__ float aT[32][68];
  __shared__ float bU[32][68];
  __shared__ float bV[32][68];
  int tid = threadIdx.x;
  int tx = tid & 15, ty = tid >> 4;
  int rowbase = blockIdx.x * 64;
  int colbase = blockIdx.y * 64;
  int sr = tid >> 2, sk = (tid & 3) * 8;
  float accU[4][4] = {}, accV[4][4] = {};
  for (int kc = 0; kc < DD; kc += 32) {
    const float* ap = A + (size_t)(rowbase + sr)*DD + kc + sk;
    float4 a0 = *(const float4*)ap;
    float4 a1 = *(const float4*)(ap + 4);
    const float* wt = gW1 + (size_t)(kc + ty)*DD + colbase + tx*4;
    const float* wb = wt + (size_t)DD*DD;
    float4 t0 = *(const float4*)wt;
    float4 t1 = *(const float4*)(wt + (size_t)16*DD);
    float4 o0 = *(const float4*)wb;
    float4 o1 = *(const float4*)(wb + (size_t)16*DD);
    __syncthreads();
    aT[sk+0][sr]=a0.x; aT[sk+1][sr]=a0.y; aT[sk+2][sr]=a0.z; aT[sk+3][sr]=a0.w;
    aT[sk+4][sr]=a1.x; aT[sk+5][sr]=a1.y; aT[sk+6][sr]=a1.z; aT[sk+7][sr]=a1.w;
    *(float4*)&bU[ty][tx*4]      = make_float4(t0.x-o0.x, t0.y-o0.y, t0.z-o0.z, t0.w-o0.w);
    *(float4*)&bU[ty + 16][tx*4] = make_float4(t1.x-o1.x, t1.y-o1.y, t1.z-o1.z, t1.w-o1.w);
    *(float4*)&bV[ty][tx*4]      = o0;
    *(float4*)&bV[ty + 16][tx*4] = o1;
    __syncthreads();
    #pragma unroll
    for (int k = 0; k < 32; k++) {
      float4 av = *(const float4*)&aT[k][ty*4];
      float4 bu = *(const float4*)&bU[k][tx*4];
      float4 bv = *(const float4*)&bV[k][tx*4];
      float a_[4] = {av.x, av.y, av.z, av.w};
      float u_[4] = {bu.x, bu.y, bu.z, bu.w};
      float v_[4] = {bv.x, bv.y, bv.z, bv.w};
      #pragma unroll
      for (int rr = 0; rr < 4; rr++)
        #pragma unroll
        for (int cc = 0; cc < 4; cc++) {
          accU[rr][cc] += a_[rr]*u_[cc];
          accV[rr][cc] += a_[rr]*v_[cc];
        }
    }
  }
  #pragma unroll
  for (int rr = 0; rr < 4; rr++) {
    int row = rowbase + ty*4 + rr;
    *(float4*)&U[(size_t)row*DD + colbase + tx*4] =
        make_float4(accU[rr][0], accU[rr][1], accU[rr][2], accU[rr][3]);
    *(float4*)&V[(size_t)row*DD + colbase + tx*4] =
        make_float4(accV[rr][0], accV[rr][1], accV[rr][2], accV[rr][3]);
  }
}

// ---------------- kNN partial (R10/R12-proven body, unchanged)
__global__ __launch_bounds__(256) void knnk(const float* __restrict__ x, const float* __restrict__ sq,
                                            float* __restrict__ pdg, int* __restrict__ pjg)
{
  __shared__ float smem[4480];
  float (*aT)[68] = (float(*)[68])smem;
  float (*bT)[68] = (float(*)[68])(smem + 2176);
  float (*dt)[65] = (float(*)[65])smem;
  float* sqI = smem + 4352;
  float* sqJ = smem + 4416;
  int tid = threadIdx.x;
  int q  = blockIdx.x & 3;
  int it = (blockIdx.x >> 2) & 31;
  int bb = blockIdx.x >> 7;
  int ibase = it * 64;
  const float* xb  = x  + (size_t)bb*NN*DD;
  const float* sqb = sq + (size_t)bb*NN;
  int tx = tid & 15, ty = tid >> 4;
  int sr = tid >> 2, sk = (tid & 3) * 8;
  int srw = sr ^ ((tid & 1) << 4);
  int selrow = tid & 63, selseg = tid >> 6;
  float bd[8]; int bj[8];
  #pragma unroll
  for (int s = 0; s < 8; s++) { bd[s] = 3.4e38f; bj[s] = 0; }
  if (tid < 64) sqI[tid] = sqb[ibase + tid];
  for (int jt = 0; jt < 8; jt++) {
    int jbase = q*512 + jt*64;
    float acc[4][4] = {};
    for (int kc = 0; kc < DD; kc += 32) {
      const float* ap = xb + (size_t)(ibase + sr)*DD + kc + sk;
      float4 a0 = *(const float4*)ap;
      float4 a1 = *(const float4*)(ap + 4);
      const float* bp = xb + (size_t)(jbase + sr)*DD + kc + sk;
      float4 b0  = *(const float4*)bp;
      float4 b1v = *(const float4*)(bp + 4);
      float sjv = 0.f;
      if (kc == 0 && tid < 64) sjv = sqb[jbase + tid];
      __syncthreads();
      aT[sk+0][srw]=a0.x; aT[sk+1][srw]=a0.y; aT[sk+2][srw]=a0.z; aT[sk+3][srw]=a0.w;
      aT[sk+4][srw]=a1.x; aT[sk+5][srw]=a1.y; aT[sk+6][srw]=a1.z; aT[sk+7][srw]=a1.w;
      bT[sk+0][srw]=b0.x; bT[sk+1][srw]=b0.y; bT[sk+2][srw]=b0.z; bT[sk+3][srw]=b0.w;
      bT[sk+4][srw]=b1v.x; bT[sk+5][srw]=b1v.y; bT[sk+6][srw]=b1v.z; bT[sk+7][srw]=b1v.w;
      if (kc == 0 && tid < 64) sqJ[tid] = sjv;
      __syncthreads();
      #pragma unroll
      for (int k = 0; k < 32; k++) {
        int rsw = ((k >> 3) & 1) << 4;
        float4 av = *(const float4*)&aT[k][(ty*4) ^ rsw];
        float4 bv = *(const float4*)&bT[k][(tx*4) ^ rsw];
        float a_[4] = {av.x, av.y, av.z, av.w};
        float b_[4] = {bv.x, bv.y, bv.z, bv.w};
        #pragma unroll
        for (int rr = 0; rr < 4; rr++)
          #pragma unroll
          for (int cc = 0; cc < 4; cc++)
            acc[rr][cc] += a_[rr]*b_[cc];
      }
    }
    __syncthreads();
    #pragma unroll
    for (int rr = 0; rr < 4; rr++)
      #pragma unroll
      for (int cc = 0; cc < 4; cc++)
        dt[ty*4+rr][tx*4+cc] = sqI[ty*4+rr] + sqJ[tx*4+cc] - 2.f*acc[rr][cc];
    __syncthreads();
    int cb = selseg*16;
    #pragma unroll
    for (int s = 0; s < 16; s++) {
      float dv = dt[selrow][cb + s];
      if (dv < bd[7]) {
        bd[7] = dv; bj[7] = jbase + cb + s;
        #pragma unroll
        for (int t = 7; t >= 1; t--) {
          if (bd[t] < bd[t-1]) {
            float td = bd[t]; bd[t] = bd[t-1]; bd[t-1] = td;
            int   tj = bj[t]; bj[t] = bj[t-1]; bj[t-1] = tj;
          }
        }
      }
    }
    __syncthreads();
  }
  float* pdl = &smem[0];
  int*   pjl = (int*)&smem[2176];
  #pragma unroll
  for (int s = 0; s < 8; s++) {
    pdl[tid*8 + s] = bd[s];
    pjl[tid*8 + s] = bj[s];
  }
  __syncthreads();
  if (tid < 64) {
    float md[8]; int mj[8];
    #pragma unroll
    for (int s = 0; s < 8; s++) { md[s] = 3.4e38f; mj[s] = 0; }
    #pragma unroll 1
    for (int g = 0; g < 4; g++) {
      int base = (g*64 + tid)*8;
      #pragma unroll
      for (int s = 0; s < 8; s++) {
        float dv = pdl[base + s];
        if (dv < md[7]) {
          md[7] = dv; mj[7] = pjl[base + s];
          #pragma unroll
          for (int t = 7; t >= 1; t--) {
            if (md[t] < md[t-1]) {
              float td = md[t]; md[t] = md[t-1]; md[t-1] = td;
              int   tj = mj[t]; mj[t] = mj[t-1]; mj[t-1] = tj;
            }
          }
        }
      }
    }
    size_t gbase = ((size_t)(bb*NN + ibase + tid))*32 + (size_t)q*8;
    #pragma unroll
    for (int s = 0; s < 8; s++) {
      pdg[gbase + s] = md[s];
      pjg[gbase + s] = bb*NN + mj[s];
    }
  }
}

// ---------------- merge 4 quarter-lists per point -> final 8 neighbor indices
__global__ __launch_bounds__(256) void knnmerge(const float* __restrict__ pdg, const int* __restrict__ pjg,
                                                int* __restrict__ idxg)
{
  int p = blockIdx.x*256 + threadIdx.x;
  float md[8]; int mj[8];
  #pragma unroll
  for (int s = 0; s < 8; s++) { md[s] = 3.4e38f; mj[s] = 0; }
  size_t base = (size_t)p*32;
  #pragma unroll 1
  for (int s = 0; s < 32; s++) {
    float dv = pdg[base + s];
    if (dv < md[7]) {
      md[7] = dv; mj[7] = pjg[base + s];
      #pragma unroll
      for (int t = 7; t >= 1; t--) {
        if (md[t] < md[t-1]) {
          float td = md[t]; md[t] = md[t-1]; md[t-1] = td;
          int   tj = mj[t]; mj[t] = mj[t-1]; mj[t-1] = tj;
        }
      }
    }
  }
  #pragma unroll
  for (int s = 0; s < 8; s++) idxg[(size_t)p*8 + s] = mj[s];
}

// ---------------- BN1 stats: h1 = relu(u_i + v_j + b1), shadow-accumulator atomics
__global__ __launch_bounds__(256) void bn1stats(const float* __restrict__ u, const float* __restrict__ v,
    const int* __restrict__ idxg, const float* __restrict__ b1, float* __restrict__ stats)
{
  __shared__ int jL[128];
  int c = threadIdx.x;
  int n0 = blockIdx.x * 16;
  if (c < 128) jL[c] = idxg[(size_t)n0*8 + c];
  __syncthreads();
  float b1c = b1[c];
  float s = 0.f, s2 = 0.f;
  #pragma unroll 1
  for (int n = 0; n < 16; n++) {
    float uc = u[(size_t)(n0 + n)*DD + c];
    #pragma unroll
    for (int e = 0; e < 8; e++) {
      int j = jL[n*8 + e];
      float h = fmaxf(uc + v[(size_t)j*DD + c] + b1c, 0.f);
      s += h; s2 += h*h;
    }
  }
  int row = blockIdx.x & (NSH - 1);
  atomicAdd(&stats[row*1024 + c], s);
  atomicAdd(&stats[row*1024 + 256 + c], s2);
}

// ---------------- fold BN1 into layer-2 weights; emit TRANSPOSED bf16 weights
// w2bf[n][k] = bf16(s1[k] * W2[k][n])  (fragment-friendly for MFMA B operand)
__global__ __launch_bounds__(256) void prep2(const float* __restrict__ stats, const float* __restrict__ g1,
    const float* __restrict__ be1, const float* __restrict__ gW2, const float* __restrict__ gb2,
    unsigned short* __restrict__ w2bf, float* __restrict__ biasp)
{
  __shared__ float s1L[256], t1L[256];
  int tid = threadIdx.x;
  const float inv = 1.f / (float)NEDGE;
  float sm = 0.f, sq2 = 0.f;
  #pragma unroll 1
  for (int r = 0; r < NSH; r++) {
    sm  += stats[r*1024 + tid];
    sq2 += stats[r*1024 + 256 + tid];
  }
  float m = sm * inv;
  float var = sq2*inv - m*m;
  float s1 = g1[tid] / sqrtf(var + BN_EPS);
  s1L[tid] = s1; t1L[tid] = be1[tid] - m*s1;
  __syncthreads();
  float bacc = gb2[tid];
  for (int k = 0; k < DD; k++) {
    float w = gW2[k*DD + tid];
    w2bf[(size_t)tid*DD + k] = f2bf(s1L[k]*w);
    bacc += t1L[k]*w;
  }
  biasp[tid] = bacc;
}

// ---------------- edge GEMM via bf16 MFMA: h2 = relu( bf16(relu(u_i+v_j+b1)) @ w2bf + bias' )
// Barrier-free K-loop: A-fragments built in registers from u/v gathers; B-fragments
// loaded directly from L2-resident w2bf. fp32 accumulate. Epilogue: pooled max/min +
// BN2 stats via block LDS reduce + shadow atomics.
__global__ __launch_bounds__(256) void edgek(
    const float* __restrict__ u, const float* __restrict__ v, const int* __restrict__ idxg,
    const float* __restrict__ b1, const unsigned short* __restrict__ w2bf,
    const float* __restrict__ biasp,
    float* __restrict__ pmaxs, float* __restrict__ pmins, float* __restrict__ stats)
{
  __shared__ float redS[4][256];
  __shared__ float redQ[4][256];
  __shared__ float redM[4][256];
  __shared__ float redN[4][256];
  int tid = threadIdx.x;
  int w = tid >> 6, lane = tid & 63;
  int m = lane & 15, quad = lane >> 4;
  int rowbase = blockIdx.x * 64;
  int edge = rowbase + w*16 + m;
  int iu = edge >> 3;
  int jv = idxg[edge];
  const float* urow = u + (size_t)iu*DD;
  const float* vrow = v + (size_t)jv*DD;
  f32x4 acc[16];
  #pragma unroll
  for (int t = 0; t < 16; t++) acc[t] = (f32x4){0.f, 0.f, 0.f, 0.f};
  #pragma unroll 1
  for (int c = 0; c < 8; c++) {
    int k0 = c*32 + quad*8;
    float4 ua = *(const float4*)(urow + k0);
    float4 ub = *(const float4*)(urow + k0 + 4);
    float4 va = *(const float4*)(vrow + k0);
    float4 vb = *(const float4*)(vrow + k0 + 4);
    float4 ba = *(const float4*)(b1 + k0);
    float4 bb = *(const float4*)(b1 + k0 + 4);
    float h0 = fmaxf(ua.x+va.x+ba.x, 0.f);
    float h1 = fmaxf(ua.y+va.y+ba.y, 0.f);
    float h2 = fmaxf(ua.z+va.z+ba.z, 0.f);
    float h3 = fmaxf(ua.w+va.w+ba.w, 0.f);
    float h4 = fmaxf(ub.x+vb.x+bb.x, 0.f);
    float h5 = fmaxf(ub.y+vb.y+bb.y, 0.f);
    float h6 = fmaxf(ub.z+vb.z+bb.z, 0.f);
    float h7 = fmaxf(ub.w+vb.w+bb.w, 0.f);
    union { bf16x8 v8; unsigned short s[8]; } af;
    af.s[0] = f2bf(h0); af.s[1] = f2bf(h1); af.s[2] = f2bf(h2); af.s[3] = f2bf(h3);
    af.s[4] = f2bf(h4); af.s[5] = f2bf(h5); af.s[6] = f2bf(h6); af.s[7] = f2bf(h7);
    #pragma unroll
    for (int nt = 0; nt < 16; nt++) {
      bf16x8 bf = *(const bf16x8*)(w2bf + (size_t)(nt*16 + m)*DD + k0);
      acc[nt] = __builtin_amdgcn_mfma_f32_16x16x32_bf16(af.v8, bf, acc[nt], 0, 0, 0);
    }
  }
  // epilogue: C layout col = m, rows = quad*4 + r (within this wave's 16-row slab)
  #pragma unroll
  for (int nt = 0; nt < 16; nt++) {
    int col = nt*16 + m;
    float bp = biasp[col];
    float r0 = fmaxf(acc[nt].x + bp, 0.f);
    float r1 = fmaxf(acc[nt].y + bp, 0.f);
    float r2 = fmaxf(acc[nt].z + bp, 0.f);
    float r3 = fmaxf(acc[nt].w + bp, 0.f);
    float mx = fmaxf(fmaxf(r0, r1), fmaxf(r2, r3));
    float mn = fminf(fminf(r0, r1), fminf(r2, r3));
    float ss = r0 + r1 + r2 + r3;
    float sq2 = r0*r0 + r1*r1 + r2*r2 + r3*r3;
    // reduce over the 4 quads holding this col (lanes m, m+16, m+32, m+48)
    mx = fmaxf(mx, __shfl_xor(mx, 16, 64));
    mx = fmaxf(mx, __shfl_xor(mx, 32, 64));
    mn = fminf(mn, __shfl_xor(mn, 16, 64));
    mn = fminf(mn, __shfl_xor(mn, 32, 64));
    ss += __shfl_xor(ss, 16, 64);
    ss += __shfl_xor(ss, 32, 64);
    sq2 += __shfl_xor(sq2, 16, 64);
    sq2 += __shfl_xor(sq2, 32, 64);
    if (quad == 0) {
      redS[w][col] = ss;
      redQ[w][col] = sq2;
      redM[w][col] = mx;
      redN[w][col] = mn;
    }
  }
  __syncthreads();
  float ts  = redS[0][tid] + redS[1][tid] + redS[2][tid] + redS[3][tid];
  float tq  = redQ[0][tid] + redQ[1][tid] + redQ[2][tid] + redQ[3][tid];
  float mxc = fmaxf(fmaxf(redM[0][tid], redM[1][tid]), fmaxf(redM[2][tid], redM[3][tid]));
  float mnc = fminf(fminf(redN[0][tid], redN[1][tid]), fminf(redN[2][tid], redN[3][tid]));
  int row = blockIdx.x & (NSH - 1);
  atomicAdd(&stats[row*1024 + 512 + tid], ts);
  atomicAdd(&stats[row*1024 + 768 + tid], tq);
  int b  = blockIdx.x >> 8;               // 256 blocks per batch
  int sh = blockIdx.x & (PSH - 1);
  atomicMax((int*)&pmaxs[((size_t)sh*BB + b)*DD + tid], __float_as_int(mxc));
  atomicMin((int*)&pmins[((size_t)sh*BB + b)*DD + tid], __float_as_int(mnc));
}

// ---------------- final: BN2 on pooled max/min, two 256x256 linears, l2norm
__global__ __launch_bounds__(256) void finalk(const float* __restrict__ pmaxs, const float* __restrict__ pmins,
    const float* __restrict__ stats, const float* __restrict__ g2, const float* __restrict__ be2,
    const float* __restrict__ W1, const float* __restrict__ b1,
    const float* __restrict__ W2, const float* __restrict__ b2,
    float* __restrict__ out)
{
  __shared__ float pl[8][256];
  __shared__ float hl[8][256];
  __shared__ float nrm[8];
  int c = threadIdx.x;
  const float inv = 1.f / (float)NEDGE;
  float sm = 0.f, sq2 = 0.f;
  #pragma unroll 1
  for (int r = 0; r < NSH; r++) {
    sm  += stats[r*1024 + 512 + c];
    sq2 += stats[r*1024 + 768 + c];
  }
  float m = sm * inv;
  float var = sq2*inv - m*m;
  float s2 = g2[c] / sqrtf(var + BN_EPS);
  float t2 = be2[c] - m*s2;
  #pragma unroll
  for (int b = 0; b < 8; b++) {
    float mx = -3.4e38f, mn = 3.4e38f;
    #pragma unroll 1
    for (int s = 0; s < PSH; s++) {
      mx = fmaxf(mx, pmaxs[((size_t)s*BB + b)*DD + c]);
      mn = fminf(mn, pmins[((size_t)s*BB + b)*DD + c]);
    }
    pl[b][c] = (s2 >= 0.f) ? s2*mx + t2 : s2*mn + t2;
  }
  __syncthreads();
  float h[8];
  #pragma unroll
  for (int b = 0; b < 8; b++) h[b] = b1[c];
  for (int k = 0; k < 256; k++) {
    float w = W1[k*256 + c];
    #pragma unroll
    for (int b = 0; b < 8; b++) h[b] += pl[b][k]*w;
  }
  __syncthreads();
  #pragma unroll
  for (int b = 0; b < 8; b++) hl[b][c] = fmaxf(h[b], 0.f);
  __syncthreads();
  float o[8];
  #pragma unroll
  for (int b = 0; b < 8; b++) o[b] = b2[c];
  for (int k = 0; k < 256; k++) {
    float w = W2[k*256 + c];
    #pragma unroll
    for (int b = 0; b < 8; b++) o[b] += hl[b][k]*w;
  }
  __syncthreads();
  #pragma unroll
  for (int b = 0; b < 8; b++) pl[b][c] = fmaxf(o[b], 0.f);
  __syncthreads();
  if (c < 8) {
    float s = 0.f;
    for (int k = 0; k < 256; k++) { float vv = pl[c][k]; s += vv*vv; }
    nrm[c] = fmaxf(sqrtf(s), 1e-12f);
  }
  __syncthreads();
  #pragma unroll
  for (int b = 0; b < 8; b++) out[b*256 + c] = pl[b][c] / nrm[b];
}

extern "C" void kernel_launch(void* const* d_in, const int* in_sizes, int n_in,
                              void* d_out, int out_size, void* d_ws, size_t ws_size,
                              hipStream_t stream) {
  (void)in_sizes; (void)n_in; (void)out_size; (void)ws_size;
  const int*   cls       = (const int*)  d_in[0];
  const float* colors    = (const float*)d_in[1];
  const float* positions = (const float*)d_in[2];
  const float* ctab      = (const float*)d_in[3];
  const float* pW1 = (const float*)d_in[4];
  const float* pb1 = (const float*)d_in[5];
  const float* pW2 = (const float*)d_in[6];
  const float* pb2 = (const float*)d_in[7];
  const float* cW1 = (const float*)d_in[8];
  const float* cb1 = (const float*)d_in[9];
  const float* cW2 = (const float*)d_in[10];
  const float* cb2 = (const float*)d_in[11];
  const float* mW  = (const float*)d_in[12];
  const float* mb  = (const float*)d_in[13];
  const float* gW1 = (const float*)d_in[14];
  const float* gb1 = (const float*)d_in[15];
  const float* gg1 = (const float*)d_in[16];
  const float* gbe1= (const float*)d_in[17];
  const float* gW2 = (const float*)d_in[18];
  const float* gb2 = (const float*)d_in[19];
  const float* gg2 = (const float*)d_in[20];
  const float* gbe2= (const float*)d_in[21];
  const float* lW1 = (const float*)d_in[22];
  const float* lb1 = (const float*)d_in[23];
  const float* lW2 = (const float*)d_in[24];
  const float* lb2 = (const float*)d_in[25];
  float* out = (float*)d_out;

  float* wsf   = (float*)d_ws;
  float* x     = wsf + OFF_X;
  float* feat  = wsf + OFF_FEAT;
  float* sq    = wsf + OFF_SQ;
  int*   idxg  = (int*)(wsf + OFF_IDX);
  float* u     = wsf + OFF_U;
  float* v     = wsf + OFF_V;
  unsigned short* w2bf = (unsigned short*)(wsf + OFF_W2BF);
  float* biasp = wsf + OFF_BIASP;
  float* stats = wsf + OFF_STATS;
  float* pmaxs = wsf + OFF_PMAXS;
  float* pmins = wsf + OFF_PMINS;
  // partial kNN buffers overlay feat (dead after the merge GEMM): 32 entries/point
  float* pdg   = feat;
  int*   pjg   = (int*)(feat + (size_t)NPTS*32);

  // stats + pmaxs + sq are contiguous -> one zero memset
  hipMemsetAsync(stats, 0, (NSH*1024 + PSH*BB*DD + NPTS)*sizeof(float), stream);
  hipMemsetAsync(pmins, 0x7f, PSH*BB*DD*sizeof(float), stream);   // ~3.39e38f

  featurize<<<NPTS/4, 256, 0, stream>>>(cls, colors, positions, ctab,
                                        pW1, pb1, pW2, pb2, cW1, cb1, cW2, cb2, feat);
  gemm64<768, true, true, true><<<dim3(NPTS/64, 4), 256, 0, stream>>>(feat, mW, mb, x, sq);
  knnk<<<BB*32*4, 256, 0, stream>>>(x, sq, pdg, pjg);
  knnmerge<<<NPTS/256, 256, 0, stream>>>(pdg, pjg, idxg);
  gemmuv<<<dim3(NPTS/64, 4), 256, 0, stream>>>(x, gW1, u, v);
  bn1stats<<<NPTS/16, 256, 0, stream>>>(u, v, idxg, gb1, stats);
  prep2<<<1, 256, 0, stream>>>(stats, gg1, gbe1, gW2, gb2, w2bf, biasp);
  edgek<<<NEDGE/64, 256, 0, stream>>>(u, v, idxg, gb1, w2bf, biasp, pmaxs, pmins, stats);
  finalk<<<1, 256, 0, stream>>>(pmaxs, pmins, stats, gg2, gbe2, lW1, lb1, lW2, lb2, out);
}